// Round 2
// baseline (8872.205 us; speedup 1.0000x reference)
//
#include <hip/hip_runtime.h>
#include <cstdint>
#include <cstddef>

constexpr int NB = 8;      // batch
constexpr int NP = 2048;   // points per cloud
constexpr int BN = NB * NP;  // 16384
constexpr int KK = 20;     // neighbors
constexpr float EPSBN = 1e-5f;
constexpr float NEG = -3.402823466e38f;

__device__ __forceinline__ float leaky(float x) { return x > 0.f ? x : 0.2f * x; }

// ---------------- transpose x [8,3,2048] -> xt [BN][4] (pad c3=0) and xtT [4][BN]
__global__ void k_transpose(const float* __restrict__ x, float* __restrict__ xt,
                            float* __restrict__ xtT) {
    int i = blockIdx.x * 256 + threadIdx.x;
    if (i >= BN) return;
    int b = i >> 11, n = i & 2047;
    float v0 = x[(b * 3 + 0) * NP + n];
    float v1 = x[(b * 3 + 1) * NP + n];
    float v2 = x[(b * 3 + 2) * NP + n];
    float4 v; v.x = v0; v.y = v1; v.z = v2; v.w = 0.f;
    *(float4*)&xt[(size_t)i * 4] = v;
    xtT[0 * BN + i] = v0;
    xtT[1 * BN + i] = v1;
    xtT[2 * BN + i] = v2;
    xtT[3 * BN + i] = 0.f;
}

// ---------------- sq[i] = |F_i|^2 from transposed features FT [CP][BN]
template <int CP>
__global__ void k_sq(const float* __restrict__ FT, float* __restrict__ sq) {
    int i = blockIdx.x * 256 + threadIdx.x;
    if (i >= BN) return;
    float s = 0.f;
#pragma unroll
    for (int c = 0; c < CP; ++c) {
        float f = FT[(size_t)c * BN + i];
        s += f * f;
    }
    sq[i] = s;
}

// ---------------- knn: top-20 farthest by q_m = sq_m - 2*dot(ctr, F_m)
// grid: NB * (NP/8) blocks, 256 threads. FT: [CP][BN] transposed features.
template <int CP>
__launch_bounds__(256)
__global__ void k_knn(const float* __restrict__ FT, const float* __restrict__ sq,
                      int* __restrict__ gidx) {
    constexpr int R = 8;
    __shared__ float ds[R][NP];   // exactly 64 KiB
    int t = threadIdx.x;
    int b = blockIdx.x >> 8;            // NP/R = 256 tiles per batch
    int n0 = (blockIdx.x & 255) * R;
    const float* FTb = FT + (size_t)b * NP;
    const float* sqb = sq + (size_t)b * NP;

    float acc[R][8];
#pragma unroll
    for (int r = 0; r < R; ++r)
#pragma unroll
        for (int mi = 0; mi < 8; ++mi) acc[r][mi] = 0.f;

    for (int cq = 0; cq < CP / 4; ++cq) {
        float4 c4[R];
#pragma unroll
        for (int r = 0; r < R; ++r) {
            c4[r].x = FTb[(size_t)(cq * 4 + 0) * BN + n0 + r];
            c4[r].y = FTb[(size_t)(cq * 4 + 1) * BN + n0 + r];
            c4[r].z = FTb[(size_t)(cq * 4 + 2) * BN + n0 + r];
            c4[r].w = FTb[(size_t)(cq * 4 + 3) * BN + n0 + r];
        }
#pragma unroll
        for (int mi = 0; mi < 8; ++mi) {
            int m = t + mi * 256;
            float f0 = FTb[(size_t)(cq * 4 + 0) * BN + m];
            float f1 = FTb[(size_t)(cq * 4 + 1) * BN + m];
            float f2 = FTb[(size_t)(cq * 4 + 2) * BN + m];
            float f3 = FTb[(size_t)(cq * 4 + 3) * BN + m];
#pragma unroll
            for (int r = 0; r < R; ++r)
                acc[r][mi] += f0 * c4[r].x + f1 * c4[r].y + f2 * c4[r].z + f3 * c4[r].w;
        }
    }
#pragma unroll
    for (int mi = 0; mi < 8; ++mi) {
        int m = t + mi * 256;
        float sm = sqb[m];
#pragma unroll
        for (int r = 0; r < R; ++r) ds[r][m] = sm - 2.f * acc[r][mi];
    }
    __syncthreads();

    // top-K: wave w handles rows 2w, 2w+1 (no further syncs needed)
    int wave = t >> 6, lane = t & 63;
#pragma unroll 1
    for (int rr = 0; rr < 2; ++rr) {
        int r = wave * 2 + rr;
        float v[32];
#pragma unroll
        for (int j = 0; j < 32; ++j) v[j] = ds[r][lane + 64 * j];
        int obase = (b * NP + n0 + r) * KK;
        for (int it = 0; it < KK; ++it) {
            float bv = NEG; int bi = 0x7fffffff;
#pragma unroll
            for (int j = 0; j < 32; ++j) {
                int m = lane + 64 * j;
                if (v[j] > bv || (v[j] == bv && m < bi)) { bv = v[j]; bi = m; }
            }
#pragma unroll
            for (int off = 32; off; off >>= 1) {
                float ov = __shfl_xor(bv, off);
                int oi = __shfl_xor(bi, off);
                if (ov > bv || (ov == bv && oi < bi)) { bv = ov; bi = oi; }
            }
            if (lane == 0) gidx[obase + it] = bi;
#pragma unroll
            for (int j = 0; j < 32; ++j)
                if (lane + 64 * j == bi) v[j] = NEG;
        }
    }
}

// ---------------- prep: W [O][2C] -> WaT [CP][O] (nbr part), WdT [CP][O] (Wb-Wa), zero-padded
__global__ void k_prepw(const float* __restrict__ W, int O, int Cact, int CP,
                        float* __restrict__ WaT, float* __restrict__ WdT) {
    int i = blockIdx.x * 256 + threadIdx.x;
    if (i >= CP * O) return;
    int c = i / O, o = i % O;
    float wa = (c < Cact) ? W[o * 2 * Cact + c] : 0.f;
    float wb = (c < Cact) ? W[o * 2 * Cact + Cact + c] : 0.f;
    WaT[i] = wa;
    WdT[i] = wb - wa;
}

// ---------------- w5 transpose: [1024][512] -> [512][1024]
__global__ void k_transw5(const float* __restrict__ w5, float* __restrict__ w5t) {
    int i = blockIdx.x * 256 + threadIdx.x;
    if (i >= 512 * 1024) return;
    int c = i >> 10, o = i & 1023;
    w5t[i] = w5[o * 512 + c];
}

// ---------------- edge conv: h[k,o] = nbr_k . Wa_o + ctr . Wd_o ; keep max_k and stats
// block = O threads; PTS points sequentially; grid = BN/PTS
template <int O, int CP>
__launch_bounds__(O)
__global__ void k_conv(const float* __restrict__ F, int ld, const int* __restrict__ gidx,
                       const float* __restrict__ WaT, const float* __restrict__ WdT,
                       float* __restrict__ hmax, float* __restrict__ s1g,
                       float* __restrict__ s2g) {
    constexpr int PTS = 8;
    constexpr int CP4 = CP / 4;
    __shared__ float nbrT[CP][KK];  // c-major neighbor tile
    __shared__ float sctr[CP];
    __shared__ int sidx[KK];
    int t = threadIdx.x;
    int p0 = blockIdx.x * PTS;
    float ts1 = 0.f, ts2 = 0.f;
    for (int p = p0; p < p0 + PTS; ++p) {
        int b = p >> 11, n = p & 2047;
        const float* Fb = F + (size_t)b * NP * ld;
        if (t < KK) sidx[t] = gidx[(size_t)p * KK + t];
        for (int c = t; c < CP; c += O) sctr[c] = Fb[(size_t)n * ld + c];
        __syncthreads();
        for (int e = t; e < KK * CP4; e += O) {
            int k = e / CP4, cq = e % CP4;
            float4 f = *(const float4*)&Fb[(size_t)sidx[k] * ld + cq * 4];
            nbrT[cq * 4 + 0][k] = f.x;
            nbrT[cq * 4 + 1][k] = f.y;
            nbrT[cq * 4 + 2][k] = f.z;
            nbrT[cq * 4 + 3][k] = f.w;
        }
        __syncthreads();
        int o = t;
        float bacc = 0.f;
#pragma unroll 4
        for (int c = 0; c < CP; ++c) bacc += sctr[c] * WdT[c * O + o];
        float acc[KK];
#pragma unroll
        for (int k = 0; k < KK; ++k) acc[k] = 0.f;
#pragma unroll 4
        for (int c = 0; c < CP; ++c) {
            float w = WaT[c * O + o];
#pragma unroll
            for (int kq = 0; kq < KK / 4; ++kq) {
                float4 f = *(const float4*)&nbrT[c][kq * 4];
                acc[kq * 4 + 0] += w * f.x;
                acc[kq * 4 + 1] += w * f.y;
                acc[kq * 4 + 2] += w * f.z;
                acc[kq * 4 + 3] += w * f.w;
            }
        }
        float hm = NEG, s1 = 0.f, s2 = 0.f;
#pragma unroll
        for (int k = 0; k < KK; ++k) {
            float h = acc[k] + bacc;
            hm = fmaxf(hm, h);
            s1 += h; s2 += h * h;
        }
        hmax[(size_t)p * O + o] = hm;
        ts1 += s1; ts2 += s2;
        __syncthreads();
    }
    atomicAdd(&s1g[t], ts1);
    atomicAdd(&s2g[t], ts2);
}

// ---------------- BN(+leaky) applied to the per-point max (monotone => commutes with max)
__global__ void k_bnmax(const float* __restrict__ hmax, int O, const float* __restrict__ s1g,
                        const float* __restrict__ s2g, const float* __restrict__ gam,
                        const float* __restrict__ bet, float* __restrict__ outc, int ostride,
                        int ooff, float inv_cnt) {
    int i = blockIdx.x * 256 + threadIdx.x;
    if (i >= BN * O) return;
    int o = i % O, p = i / O;
    float m = s1g[o] * inv_cnt;
    float v = s2g[o] * inv_cnt - m * m;
    float rs = rsqrtf(v + EPSBN);
    float y = gam[o] * (hmax[i] - m) * rs + bet[o];
    outc[(size_t)p * ostride + ooff + o] = leaky(y);
}

// ---------------- tiled transpose: in [BN][ld] cols [0,O) -> out [O][BN]
__global__ void k_xpose(const float* __restrict__ in, int ld, float* __restrict__ out) {
    __shared__ float tile[64][65];
    int tx = threadIdx.x & 63, ty = threadIdx.x >> 6;
    int p0 = blockIdx.x * 64, o0 = blockIdx.y * 64;
    for (int i = ty; i < 64; i += 4)
        tile[i][tx] = in[(size_t)(p0 + i) * ld + o0 + tx];
    __syncthreads();
    for (int i = ty; i < 64; i += 4)
        out[(size_t)(o0 + i) * BN + p0 + tx] = tile[tx][i];
}

// ---------------- w5 GEMM: g5 = hc [BN][512] @ w5t [512][1024], plus channel stats
__launch_bounds__(256)
__global__ void k_w5(const float* __restrict__ hc, const float* __restrict__ w5t,
                     float* __restrict__ g5, float* __restrict__ s1g, float* __restrict__ s2g) {
    constexpr int PTS = 16;
    __shared__ float hT[512][20];  // pitch 20: dodge bank conflicts
    int t = threadIdx.x;
    int ot = blockIdx.x & 3;
    int p0 = (blockIdx.x >> 2) * PTS;
    int o = ot * 256 + t;
    for (int e = t; e < PTS * 128; e += 256) {
        int p = e >> 7, cq = e & 127;
        float4 f = *(const float4*)&hc[(size_t)(p0 + p) * 512 + cq * 4];
        hT[cq * 4 + 0][p] = f.x;
        hT[cq * 4 + 1][p] = f.y;
        hT[cq * 4 + 2][p] = f.z;
        hT[cq * 4 + 3][p] = f.w;
    }
    __syncthreads();
    float acc[PTS];
#pragma unroll
    for (int p = 0; p < PTS; ++p) acc[p] = 0.f;
#pragma unroll 2
    for (int c = 0; c < 512; ++c) {
        float w = w5t[c * 1024 + o];
#pragma unroll
        for (int pq = 0; pq < PTS / 4; ++pq) {
            float4 f = *(const float4*)&hT[c][pq * 4];
            acc[pq * 4 + 0] += w * f.x;
            acc[pq * 4 + 1] += w * f.y;
            acc[pq * 4 + 2] += w * f.z;
            acc[pq * 4 + 3] += w * f.w;
        }
    }
    float ts1 = 0.f, ts2 = 0.f;
#pragma unroll
    for (int p = 0; p < PTS; ++p) {
        float v = acc[p];
        g5[(size_t)(p0 + p) * 1024 + o] = v;
        ts1 += v; ts2 += v * v;
    }
    atomicAdd(&s1g[o], ts1);
    atomicAdd(&s2g[o], ts2);
}

// ---------------- pool: per (b, o-tile, n-chunk) partial max / partial sum of leaky(bn(g))
__global__ void k_pool(const float* __restrict__ gbuf, const float* __restrict__ s1g,
                       const float* __restrict__ s2g, const float* __restrict__ gam,
                       const float* __restrict__ bet, float* __restrict__ pmax,
                       float* __restrict__ psum) {
    int t = threadIdx.x;
    int blk = blockIdx.x;
    int nc = blk & 7, ot = (blk >> 3) & 3, b = blk >> 5;
    int o = ot * 256 + t;
    float m = s1g[o] * (1.f / 16384.f);
    float v = s2g[o] * (1.f / 16384.f) - m * m;
    float rs = rsqrtf(v + EPSBN);
    float ga = gam[o], be = bet[o];
    float vmax = NEG, vsum = 0.f;
    for (int j = 0; j < 256; ++j) {
        int n = nc * 256 + j;
        float x = gbuf[((size_t)b * NP + n) * 1024 + o];
        float y = leaky(ga * (x - m) * rs + be);
        vmax = fmaxf(vmax, y);
        vsum += y;
    }
    pmax[(b * 1024 + o) * 8 + nc] = vmax;
    psum[(b * 1024 + o) * 8 + nc] = vsum;
}

__global__ void k_poolfin(const float* __restrict__ pmax, const float* __restrict__ psum,
                          float* __restrict__ pooled) {
    int i = blockIdx.x * 256 + threadIdx.x;
    if (i >= 8192) return;
    float mx = NEG, sm = 0.f;
    for (int j = 0; j < 8; ++j) {
        mx = fmaxf(mx, pmax[i * 8 + j]);
        sm += psum[i * 8 + j];
    }
    int b = i >> 10, o = i & 1023;
    pooled[b * 2048 + o] = mx;
    pooled[b * 2048 + 1024 + o] = sm * (1.f / 2048.f);
}

// ---------------- small FC: z[b][o] = in[b] . W[o] (+bias)
template <int CIN>
__global__ void k_fc(const float* __restrict__ in, const float* __restrict__ W,
                     const float* __restrict__ bias, int O, float* __restrict__ z) {
    int i = blockIdx.x * 256 + threadIdx.x;
    if (i >= NB * O) return;
    int b = i / O, o = i % O;
    const float* wr = W + (size_t)o * CIN;
    const float* ir = in + (size_t)b * CIN;
    float acc = 0.f;
#pragma unroll 4
    for (int cq = 0; cq < CIN / 4; ++cq) {
        float4 wv = *(const float4*)&wr[cq * 4];
        float4 iv = *(const float4*)&ir[cq * 4];
        acc += wv.x * iv.x + wv.y * iv.y + wv.z * iv.z + wv.w * iv.w;
    }
    z[i] = acc + (bias ? bias[o] : 0.f);
}

// ---------------- BN over batch (8 samples) + leaky, write with stride/offset
__global__ void k_bnb(const float* __restrict__ z, int O, const float* __restrict__ gam,
                      const float* __restrict__ bet, float* __restrict__ out, int ostride,
                      int ooff) {
    int o = blockIdx.x * 256 + threadIdx.x;
    if (o >= O) return;
    float s1 = 0.f, s2 = 0.f;
#pragma unroll
    for (int b = 0; b < NB; ++b) {
        float x = z[b * O + o];
        s1 += x; s2 += x * x;
    }
    float m = s1 * 0.125f, v = s2 * 0.125f - m * m;
    float rs = rsqrtf(v + EPSBN);
    float ga = gam[o], be = bet[o];
    for (int b = 0; b < NB; ++b) {
        float y = ga * (z[b * O + o] - m) * rs + be;
        out[b * ostride + ooff + o] = leaky(y);
    }
}

// ---------------- head: [8,768] @ whead.T + bhead, BN over batch, ReLU -> out [8,7]
__global__ void k_head(const float* __restrict__ hf, const float* __restrict__ wh,
                       const float* __restrict__ bh, const float* __restrict__ g8,
                       const float* __restrict__ b8, float* __restrict__ out) {
    __shared__ float zh[56];
    int t = threadIdx.x;
    if (t < 56) {
        int b = t / 7, o = t % 7;
        float acc = bh[o];
        for (int c = 0; c < 768; ++c) acc += hf[b * 768 + c] * wh[o * 768 + c];
        zh[t] = acc;
    }
    __syncthreads();
    if (t < 7) {
        float s1 = 0.f, s2 = 0.f;
        for (int b = 0; b < NB; ++b) {
            float x = zh[b * 7 + t];
            s1 += x; s2 += x * x;
        }
        float m = s1 * 0.125f, v = s2 * 0.125f - m * m;
        float rs = rsqrtf(v + EPSBN);
        for (int b = 0; b < NB; ++b) {
            float y = g8[t] * (zh[b * 7 + t] - m) * rs + b8[t];
            out[b * 7 + t] = fmaxf(y, 0.f);
        }
    }
}

extern "C" void kernel_launch(void* const* d_in, const int* in_sizes, int n_in, void* d_out,
                              int out_size, void* d_ws, size_t ws_size, hipStream_t stream) {
    const float* x[3] = {(const float*)d_in[0], (const float*)d_in[1], (const float*)d_in[2]};
    const float* w1 = (const float*)d_in[3];
    const float* w2 = (const float*)d_in[4];
    const float* w3 = (const float*)d_in[5];
    const float* w4 = (const float*)d_in[6];
    const float* w5 = (const float*)d_in[7];
    const float* wl1 = (const float*)d_in[8];
    const float* wl2 = (const float*)d_in[9];
    const float* bl2 = (const float*)d_in[10];
    const float* whead = (const float*)d_in[11];
    const float* bhead = (const float*)d_in[12];
    const float *g1 = (const float*)d_in[13], *b1 = (const float*)d_in[14];
    const float *g2 = (const float*)d_in[15], *b2 = (const float*)d_in[16];
    const float *g3 = (const float*)d_in[17], *b3 = (const float*)d_in[18];
    const float *g4 = (const float*)d_in[19], *b4 = (const float*)d_in[20];
    const float *g5 = (const float*)d_in[21], *b5 = (const float*)d_in[22];
    const float *g6 = (const float*)d_in[23], *b6 = (const float*)d_in[24];
    const float *g7 = (const float*)d_in[25], *b7 = (const float*)d_in[26];
    const float *g8 = (const float*)d_in[27], *b8 = (const float*)d_in[28];

    char* w = (char*)d_ws;
    auto alloc = [&](size_t bytes) {
        char* p = w;
        w += (bytes + 255) & ~(size_t)255;
        return p;
    };
    float* xt   = (float*)alloc((size_t)BN * 4 * 4);
    float* xtT  = (float*)alloc((size_t)4 * BN * 4);
    float* hc   = (float*)alloc((size_t)BN * 512 * 4);
    float* hcT  = (float*)alloc((size_t)128 * BN * 4);
    float* gbig = (float*)alloc((size_t)BN * 1024 * 4);  // hmax (<=16MB) then g5 (64MB)
    int*   idx  = (int*)alloc((size_t)BN * KK * 4);
    float* sqv  = (float*)alloc((size_t)BN * 4);
    float* s1g  = (float*)alloc(1024 * 4);
    float* s2g  = (float*)alloc(1024 * 4);
    float* pmax = (float*)alloc(8 * 1024 * 8 * 4);
    float* psum = (float*)alloc(8 * 1024 * 8 * 4);
    float* pooled = (float*)alloc(8 * 2048 * 4);
    float* z1 = (float*)alloc(8 * 512 * 4);
    float* a1 = (float*)alloc(8 * 512 * 4);
    float* z2 = (float*)alloc(8 * 256 * 4);
    float* hfeat = (float*)alloc(8 * 768 * 4);
    float* Wa1 = (float*)alloc(4 * 64 * 4);
    float* Wd1 = (float*)alloc(4 * 64 * 4);
    float* Wa2 = (float*)alloc(64 * 64 * 4);
    float* Wd2 = (float*)alloc(64 * 64 * 4);
    float* Wa3 = (float*)alloc(64 * 128 * 4);
    float* Wd3 = (float*)alloc(64 * 128 * 4);
    float* Wa4 = (float*)alloc(128 * 256 * 4);
    float* Wd4 = (float*)alloc(128 * 256 * 4);
    float* w5t = (float*)alloc(512 * 1024 * 4);

    // weight prep (plane-independent)
    k_prepw<<<(4 * 64 + 255) / 256, 256, 0, stream>>>(w1, 64, 3, 4, Wa1, Wd1);
    k_prepw<<<(64 * 64 + 255) / 256, 256, 0, stream>>>(w2, 64, 64, 64, Wa2, Wd2);
    k_prepw<<<(64 * 128 + 255) / 256, 256, 0, stream>>>(w3, 128, 64, 64, Wa3, Wd3);
    k_prepw<<<(128 * 256 + 255) / 256, 256, 0, stream>>>(w4, 256, 128, 128, Wa4, Wd4);
    k_transw5<<<(512 * 1024) / 256, 256, 0, stream>>>(w5, w5t);

    const float inv_e = 1.f / (float)(BN * KK);
    for (int p = 0; p < 3; ++p) {
        k_transpose<<<BN / 256, 256, 0, stream>>>(x[p], xt, xtT);

        // ---- layer 1: F = xt (C=3 padded to 4), O=64 -> hc[:, 0:64]
        k_sq<4><<<BN / 256, 256, 0, stream>>>(xtT, sqv);
        k_knn<4><<<NB * (NP / 8), 256, 0, stream>>>(xtT, sqv, idx);
        hipMemsetAsync(s1g, 0, 8192, stream);
        k_conv<64, 4><<<BN / 8, 64, 0, stream>>>(xt, 4, idx, Wa1, Wd1, gbig, s1g, s2g);
        k_bnmax<<<(BN * 64) / 256, 256, 0, stream>>>(gbig, 64, s1g, s2g, g1, b1, hc, 512, 0, inv_e);
        k_xpose<<<dim3(BN / 64, 1), 256, 0, stream>>>(hc + 0, 512, hcT);

        // ---- layer 2: F = h1 (64), O=64 -> hc[:, 64:128]
        k_sq<64><<<BN / 256, 256, 0, stream>>>(hcT, sqv);
        k_knn<64><<<NB * (NP / 8), 256, 0, stream>>>(hcT, sqv, idx);
        hipMemsetAsync(s1g, 0, 8192, stream);
        k_conv<64, 64><<<BN / 8, 64, 0, stream>>>(hc + 0, 512, idx, Wa2, Wd2, gbig, s1g, s2g);
        k_bnmax<<<(BN * 64) / 256, 256, 0, stream>>>(gbig, 64, s1g, s2g, g2, b2, hc, 512, 64, inv_e);
        k_xpose<<<dim3(BN / 64, 1), 256, 0, stream>>>(hc + 64, 512, hcT);

        // ---- layer 3: F = h2 (64), O=128 -> hc[:, 128:256]
        k_sq<64><<<BN / 256, 256, 0, stream>>>(hcT, sqv);
        k_knn<64><<<NB * (NP / 8), 256, 0, stream>>>(hcT, sqv, idx);
        hipMemsetAsync(s1g, 0, 8192, stream);
        k_conv<128, 64><<<BN / 8, 128, 0, stream>>>(hc + 64, 512, idx, Wa3, Wd3, gbig, s1g, s2g);
        k_bnmax<<<(BN * 128) / 256, 256, 0, stream>>>(gbig, 128, s1g, s2g, g3, b3, hc, 512, 128, inv_e);
        k_xpose<<<dim3(BN / 64, 2), 256, 0, stream>>>(hc + 128, 512, hcT);

        // ---- layer 4: F = h3 (128), O=256 -> hc[:, 256:512]
        k_sq<128><<<BN / 256, 256, 0, stream>>>(hcT, sqv);
        k_knn<128><<<NB * (NP / 8), 256, 0, stream>>>(hcT, sqv, idx);
        hipMemsetAsync(s1g, 0, 8192, stream);
        k_conv<256, 128><<<BN / 8, 256, 0, stream>>>(hc + 128, 512, idx, Wa4, Wd4, gbig, s1g, s2g);
        k_bnmax<<<(BN * 256) / 256, 256, 0, stream>>>(gbig, 256, s1g, s2g, g4, b4, hc, 512, 256, inv_e);

        // ---- w5 + BN + pool
        hipMemsetAsync(s1g, 0, 8192, stream);
        k_w5<<<(BN / 16) * 4, 256, 0, stream>>>(hc, w5t, gbig, s1g, s2g);
        k_pool<<<256, 256, 0, stream>>>(gbig, s1g, s2g, g5, b5, pmax, psum);
        k_poolfin<<<32, 256, 0, stream>>>(pmax, psum, pooled);

        // ---- FC head of the plane
        k_fc<2048><<<(8 * 512 + 255) / 256, 256, 0, stream>>>(pooled, wl1, nullptr, 512, z1);
        k_bnb<<<2, 256, 0, stream>>>(z1, 512, g6, b6, a1, 512, 0);
        k_fc<512><<<(8 * 256 + 255) / 256, 256, 0, stream>>>(a1, wl2, bl2, 256, z2);
        k_bnb<<<1, 256, 0, stream>>>(z2, 256, g7, b7, hfeat, 768, p * 256);
    }
    k_head<<<1, 64, 0, stream>>>(hfeat, whead, bhead, g8, b8, (float*)d_out);
}

// Round 5
// 5958.879 us; speedup vs baseline: 1.4889x; 1.4889x over previous
//
#include <hip/hip_runtime.h>
#include <cstdint>
#include <cstddef>

constexpr int NB = 8;      // batch
constexpr int NP = 2048;   // points per cloud
constexpr int BN = NB * NP;  // 16384
constexpr int KK = 20;     // neighbors
constexpr float EPSBN = 1e-5f;
constexpr float NEG = -3.402823466e38f;
constexpr int SLOTS = 8;   // atomic-contention spreading for conv stats

__device__ __forceinline__ float leaky(float x) { return x > 0.f ? x : 0.2f * x; }

// float -> orderable u32 (ascending uint == ascending float)
__device__ __forceinline__ unsigned int f2key(float f) {
    unsigned int u = __float_as_uint(f);
    return u ^ (unsigned int)(((int)u >> 31) | 0x80000000);
}

// ---------------- transpose x [8,3,2048] -> xt [BN][4] (pad c3=0) and xtT [4][BN]
__global__ void k_transpose(const float* __restrict__ x, float* __restrict__ xt,
                            float* __restrict__ xtT) {
    int i = blockIdx.x * 256 + threadIdx.x;
    if (i >= BN) return;
    int b = i >> 11, n = i & 2047;
    float v0 = x[(b * 3 + 0) * NP + n];
    float v1 = x[(b * 3 + 1) * NP + n];
    float v2 = x[(b * 3 + 2) * NP + n];
    float4 v; v.x = v0; v.y = v1; v.z = v2; v.w = 0.f;
    *(float4*)&xt[(size_t)i * 4] = v;
    xtT[0 * BN + i] = v0;
    xtT[1 * BN + i] = v1;
    xtT[2 * BN + i] = v2;
    xtT[3 * BN + i] = 0.f;
}

// ---------------- sq[i] = |F_i|^2 from transposed features FT [CP][BN]
template <int CP>
__global__ void k_sq(const float* __restrict__ FT, float* __restrict__ sq) {
    int i = blockIdx.x * 256 + threadIdx.x;
    if (i >= BN) return;
    float s = 0.f;
#pragma unroll
    for (int c = 0; c < CP; ++c) {
        float f = FT[(size_t)c * BN + i];
        s += f * f;
    }
    sq[i] = s;
}

// ---------------- knn: top-20 farthest by q_m = sq_m - 2*dot(ctr, F_m)
// Distance phase identical to round-2 (bit-identical q values). Selection via
// 32-bit radix descend on orderable keys + ballot compaction (set semantics;
// ties resolved to smallest index, matching top_k).
template <int CP>
__launch_bounds__(256, 2)
__global__ void k_knn(const float* __restrict__ FT, const float* __restrict__ sq,
                      int* __restrict__ gidx) {
    constexpr int R = 8;
    __shared__ unsigned int ds[R][NP];   // 64 KiB of keys
    int t = threadIdx.x;
    int b = blockIdx.x >> 8;            // NP/R = 256 tiles per batch
    int n0 = (blockIdx.x & 255) * R;
    const float* FTb = FT + (size_t)b * NP;
    const float* sqb = sq + (size_t)b * NP;

    float acc[R][8];
#pragma unroll
    for (int r = 0; r < R; ++r)
#pragma unroll
        for (int mi = 0; mi < 8; ++mi) acc[r][mi] = 0.f;

    for (int cq = 0; cq < CP / 4; ++cq) {
        float4 c4[R];
#pragma unroll
        for (int r = 0; r < R; ++r) {
            c4[r].x = FTb[(size_t)(cq * 4 + 0) * BN + n0 + r];
            c4[r].y = FTb[(size_t)(cq * 4 + 1) * BN + n0 + r];
            c4[r].z = FTb[(size_t)(cq * 4 + 2) * BN + n0 + r];
            c4[r].w = FTb[(size_t)(cq * 4 + 3) * BN + n0 + r];
        }
#pragma unroll
        for (int mi = 0; mi < 8; ++mi) {
            int m = t + mi * 256;
            float f0 = FTb[(size_t)(cq * 4 + 0) * BN + m];
            float f1 = FTb[(size_t)(cq * 4 + 1) * BN + m];
            float f2 = FTb[(size_t)(cq * 4 + 2) * BN + m];
            float f3 = FTb[(size_t)(cq * 4 + 3) * BN + m];
#pragma unroll
            for (int r = 0; r < R; ++r)
                acc[r][mi] += f0 * c4[r].x + f1 * c4[r].y + f2 * c4[r].z + f3 * c4[r].w;
        }
    }
#pragma unroll
    for (int mi = 0; mi < 8; ++mi) {
        int m = t + mi * 256;
        float sm = sqb[m];
#pragma unroll
        for (int r = 0; r < R; ++r) ds[r][m] = f2key(sm - 2.f * acc[r][mi]);
    }
    __syncthreads();

    // selection: wave w handles rows 2w, 2w+1
    int wave = t >> 6, lane = t & 63;
    unsigned long long below = (1ull << lane) - 1ull;
#pragma unroll 1
    for (int rr = 0; rr < 2; ++rr) {
        int r = wave * 2 + rr;
        unsigned int kv[32];
#pragma unroll
        for (int j = 0; j < 32; ++j) kv[j] = ds[r][lane + 64 * j];

        // radix descend: T = rank-K (K-th largest) key value
        unsigned int T = 0;
#pragma unroll 1
        for (int bit = 31; bit >= 0; --bit) {
            unsigned int tt = T | (1u << bit);
            int c = 0;
#pragma unroll
            for (int j = 0; j < 32; ++j)
                c += (int)__popcll(__ballot(kv[j] >= tt));
            if (c >= KK) T = tt;
        }

        int obase = (b * NP + n0 + r) * KK;
        // pass 1: strictly greater -> all selected
        int base = 0;
#pragma unroll 1
        for (int j = 0; j < 32; ++j) {
            bool pg = kv[j] > T;
            unsigned long long mk = __ballot(pg);
            if (pg) gidx[obase + base + (int)__popcll(mk & below)] = lane + 64 * j;
            base += (int)__popcll(mk);
        }
        // pass 2: equals, take smallest indices (ascending m = ascending (j,lane))
        int rem = KK - base;
#pragma unroll 1
        for (int j = 0; j < 32; ++j) {
            if (rem <= 0) break;
            bool pe = kv[j] == T;
            unsigned long long mk = __ballot(pe);
            int myp = (int)__popcll(mk & below);
            if (pe && myp < rem) gidx[obase + base + myp] = lane + 64 * j;
            int cnt = (int)__popcll(mk);
            int take = cnt < rem ? cnt : rem;
            base += take; rem -= take;
        }
    }
}

// ---------------- prep: W [O][2C] -> WaT [CP][O] (nbr part), WdT [CP][O] (Wb-Wa), zero-padded
__global__ void k_prepw(const float* __restrict__ W, int O, int Cact, int CP,
                        float* __restrict__ WaT, float* __restrict__ WdT) {
    int i = blockIdx.x * 256 + threadIdx.x;
    if (i >= CP * O) return;
    int c = i / O, o = i % O;
    float wa = (c < Cact) ? W[o * 2 * Cact + c] : 0.f;
    float wb = (c < Cact) ? W[o * 2 * Cact + Cact + c] : 0.f;
    WaT[i] = wa;
    WdT[i] = wb - wa;
}

// ---------------- w5 transpose: [1024][512] -> [512][1024]
__global__ void k_transw5(const float* __restrict__ w5, float* __restrict__ w5t) {
    int i = blockIdx.x * 256 + threadIdx.x;
    if (i >= 512 * 1024) return;
    int c = i >> 10, o = i & 1023;
    w5t[i] = w5[o * 512 + c];
}

// ---------------- edge conv: h[k,o] = nbr_k . Wa_o + ctr . Wd_o ; keep max_k and stats
// One block per 2 points (weights streamed once per 2 points). k-dim padded to
// 32 with rotate swizzle k' = (k + 4*(cq&7))&31 -> aligned b128 broadcast reads,
// ~4-way (not 16-way) write conflicts.
template <int O, int CP>
__launch_bounds__(O)
__global__ void k_conv(const float* __restrict__ F, int ld, const int* __restrict__ gidx,
                       const float* __restrict__ WaT, const float* __restrict__ WdT,
                       float* __restrict__ hmax, float* __restrict__ s1p,
                       float* __restrict__ s2p) {
    constexpr int CP4 = CP / 4;
    __shared__ float nbrT[2][CP][32];
    __shared__ float sctr[2][CP];
    __shared__ int sidx[2][KK];
    int t = threadIdx.x;
    int p0 = blockIdx.x * 2;
    int b = p0 >> 11;
    const float* Fb = F + (size_t)b * NP * ld;

    if (t < 2 * KK) {
        int pt = t / KK, k = t % KK;
        sidx[pt][k] = gidx[(size_t)(p0 + pt) * KK + k];
    }
    for (int e = t; e < 2 * CP; e += O) {
        int pt = e / CP, cc = e % CP;
        int n = (p0 + pt) & 2047;
        sctr[pt][cc] = Fb[(size_t)n * ld + cc];
    }
    __syncthreads();
    for (int e = t; e < 2 * KK * CP4; e += O) {
        int pt = e / (KK * CP4);
        int e2 = e % (KK * CP4);
        int k = e2 / CP4, cq = e2 % CP4;
        float4 f = *(const float4*)&Fb[(size_t)sidx[pt][k] * ld + cq * 4];
        int kp = (k + 4 * (cq & 7)) & 31;
        nbrT[pt][cq * 4 + 0][kp] = f.x;
        nbrT[pt][cq * 4 + 1][kp] = f.y;
        nbrT[pt][cq * 4 + 2][kp] = f.z;
        nbrT[pt][cq * 4 + 3][kp] = f.w;
    }
    __syncthreads();

    int o = t;
    float bacc0 = 0.f, bacc1 = 0.f;
#pragma unroll 4
    for (int c = 0; c < CP; ++c) {
        float w = WdT[c * O + o];
        bacc0 += sctr[0][c] * w;
        bacc1 += sctr[1][c] * w;
    }
    float a0[KK], a1[KK];
#pragma unroll
    for (int k = 0; k < KK; ++k) { a0[k] = 0.f; a1[k] = 0.f; }
#pragma unroll 2
    for (int c = 0; c < CP; ++c) {
        float w = WaT[c * O + o];
        int s = 4 * ((c >> 2) & 7);
#pragma unroll
        for (int kq = 0; kq < KK / 4; ++kq) {
            int kp = (4 * kq + s) & 31;
            float4 f0 = *(const float4*)&nbrT[0][c][kp];
            float4 f1 = *(const float4*)&nbrT[1][c][kp];
            a0[kq * 4 + 0] += w * f0.x; a1[kq * 4 + 0] += w * f1.x;
            a0[kq * 4 + 1] += w * f0.y; a1[kq * 4 + 1] += w * f1.y;
            a0[kq * 4 + 2] += w * f0.z; a1[kq * 4 + 2] += w * f1.z;
            a0[kq * 4 + 3] += w * f0.w; a1[kq * 4 + 3] += w * f1.w;
        }
    }
    float hm0 = NEG, hm1 = NEG, ts1 = 0.f, ts2 = 0.f;
#pragma unroll
    for (int k = 0; k < KK; ++k) {
        float h0 = a0[k] + bacc0;
        float h1 = a1[k] + bacc1;
        hm0 = fmaxf(hm0, h0); hm1 = fmaxf(hm1, h1);
        ts1 += h0 + h1; ts2 += h0 * h0 + h1 * h1;
    }
    hmax[(size_t)p0 * O + o] = hm0;
    hmax[(size_t)(p0 + 1) * O + o] = hm1;
    int slot = blockIdx.x & (SLOTS - 1);
    atomicAdd(&s1p[slot * O + o], ts1);
    atomicAdd(&s2p[slot * O + o], ts2);
}

// ---------------- BN(+leaky) applied to the per-point max (monotone => commutes with max)
__global__ void k_bnmax(const float* __restrict__ hmax, int O, const float* __restrict__ s1p,
                        const float* __restrict__ s2p, const float* __restrict__ gam,
                        const float* __restrict__ bet, float* __restrict__ outc, int ostride,
                        int ooff, float inv_cnt) {
    int i = blockIdx.x * 256 + threadIdx.x;
    if (i >= BN * O) return;
    int o = i % O, p = i / O;
    float s1 = 0.f, s2 = 0.f;
#pragma unroll
    for (int s = 0; s < SLOTS; ++s) { s1 += s1p[s * O + o]; s2 += s2p[s * O + o]; }
    float m = s1 * inv_cnt;
    float v = s2 * inv_cnt - m * m;
    float rs = rsqrtf(v + EPSBN);
    float y = gam[o] * (hmax[i] - m) * rs + bet[o];
    outc[(size_t)p * ostride + ooff + o] = leaky(y);
}

// ---------------- tiled transpose: in [BN][ld] cols [0,O) -> out [O][BN]
__global__ void k_xpose(const float* __restrict__ in, int ld, float* __restrict__ out) {
    __shared__ float tile[64][65];
    int tx = threadIdx.x & 63, ty = threadIdx.x >> 6;
    int p0 = blockIdx.x * 64, o0 = blockIdx.y * 64;
    for (int i = ty; i < 64; i += 4)
        tile[i][tx] = in[(size_t)(p0 + i) * ld + o0 + tx];
    __syncthreads();
    for (int i = ty; i < 64; i += 4)
        out[(size_t)(o0 + i) * BN + p0 + tx] = tile[tx][i];
}

// ---------------- w5 GEMM: g5 = hc [BN][512] @ w5t [512][1024], plus channel stats
__launch_bounds__(256)
__global__ void k_w5(const float* __restrict__ hc, const float* __restrict__ w5t,
                     float* __restrict__ g5, float* __restrict__ s1g, float* __restrict__ s2g) {
    constexpr int PTS = 16;
    __shared__ float hT[512][20];  // pitch 20: dodge bank conflicts
    int t = threadIdx.x;
    int ot = blockIdx.x & 3;
    int p0 = (blockIdx.x >> 2) * PTS;
    int o = ot * 256 + t;
    for (int e = t; e < PTS * 128; e += 256) {
        int p = e >> 7, cq = e & 127;
        float4 f = *(const float4*)&hc[(size_t)(p0 + p) * 512 + cq * 4];
        hT[cq * 4 + 0][p] = f.x;
        hT[cq * 4 + 1][p] = f.y;
        hT[cq * 4 + 2][p] = f.z;
        hT[cq * 4 + 3][p] = f.w;
    }
    __syncthreads();
    float acc[PTS];
#pragma unroll
    for (int p = 0; p < PTS; ++p) acc[p] = 0.f;
#pragma unroll 2
    for (int c = 0; c < 512; ++c) {
        float w = w5t[c * 1024 + o];
#pragma unroll
        for (int pq = 0; pq < PTS / 4; ++pq) {
            float4 f = *(const float4*)&hT[c][pq * 4];
            acc[pq * 4 + 0] += w * f.x;
            acc[pq * 4 + 1] += w * f.y;
            acc[pq * 4 + 2] += w * f.z;
            acc[pq * 4 + 3] += w * f.w;
        }
    }
    float ts1 = 0.f, ts2 = 0.f;
#pragma unroll
    for (int p = 0; p < PTS; ++p) {
        float v = acc[p];
        g5[(size_t)(p0 + p) * 1024 + o] = v;
        ts1 += v; ts2 += v * v;
    }
    atomicAdd(&s1g[o], ts1);
    atomicAdd(&s2g[o], ts2);
}

// ---------------- pool: per (b, o-tile, n-chunk) partial max / partial sum of leaky(bn(g))
__global__ void k_pool(const float* __restrict__ gbuf, const float* __restrict__ s1g,
                       const float* __restrict__ s2g, const float* __restrict__ gam,
                       const float* __restrict__ bet, float* __restrict__ pmax,
                       float* __restrict__ psum) {
    int t = threadIdx.x;
    int blk = blockIdx.x;
    int nc = blk & 7, ot = (blk >> 3) & 3, b = blk >> 5;
    int o = ot * 256 + t;
    float m = s1g[o] * (1.f / 16384.f);
    float v = s2g[o] * (1.f / 16384.f) - m * m;
    float rs = rsqrtf(v + EPSBN);
    float ga = gam[o], be = bet[o];
    float vmax = NEG, vsum = 0.f;
    for (int j = 0; j < 256; ++j) {
        int n = nc * 256 + j;
        float x = gbuf[((size_t)b * NP + n) * 1024 + o];
        float y = leaky(ga * (x - m) * rs + be);
        vmax = fmaxf(vmax, y);
        vsum += y;
    }
    pmax[(b * 1024 + o) * 8 + nc] = vmax;
    psum[(b * 1024 + o) * 8 + nc] = vsum;
}

__global__ void k_poolfin(const float* __restrict__ pmax, const float* __restrict__ psum,
                          float* __restrict__ pooled) {
    int i = blockIdx.x * 256 + threadIdx.x;
    if (i >= 8192) return;
    float mx = NEG, sm = 0.f;
    for (int j = 0; j < 8; ++j) {
        mx = fmaxf(mx, pmax[i * 8 + j]);
        sm += psum[i * 8 + j];
    }
    int b = i >> 10, o = i & 1023;
    pooled[b * 2048 + o] = mx;
    pooled[b * 2048 + 1024 + o] = sm * (1.f / 2048.f);
}

// ---------------- small FC: z[b][o] = in[b] . W[o] (+bias)
template <int CIN>
__global__ void k_fc(const float* __restrict__ in, const float* __restrict__ W,
                     const float* __restrict__ bias, int O, float* __restrict__ z) {
    int i = blockIdx.x * 256 + threadIdx.x;
    if (i >= NB * O) return;
    int b = i / O, o = i % O;
    const float* wr = W + (size_t)o * CIN;
    const float* ir = in + (size_t)b * CIN;
    float acc = 0.f;
#pragma unroll 4
    for (int cq = 0; cq < CIN / 4; ++cq) {
        float4 wv = *(const float4*)&wr[cq * 4];
        float4 iv = *(const float4*)&ir[cq * 4];
        acc += wv.x * iv.x + wv.y * iv.y + wv.z * iv.z + wv.w * iv.w;
    }
    z[i] = acc + (bias ? bias[o] : 0.f);
}

// ---------------- BN over batch (8 samples) + leaky, write with stride/offset
__global__ void k_bnb(const float* __restrict__ z, int O, const float* __restrict__ gam,
                      const float* __restrict__ bet, float* __restrict__ out, int ostride,
                      int ooff) {
    int o = blockIdx.x * 256 + threadIdx.x;
    if (o >= O) return;
    float s1 = 0.f, s2 = 0.f;
#pragma unroll
    for (int b = 0; b < NB; ++b) {
        float x = z[b * O + o];
        s1 += x; s2 += x * x;
    }
    float m = s1 * 0.125f, v = s2 * 0.125f - m * m;
    float rs = rsqrtf(v + EPSBN);
    float ga = gam[o], be = bet[o];
    for (int b = 0; b < NB; ++b) {
        float y = ga * (z[b * O + o] - m) * rs + be;
        out[b * ostride + ooff + o] = leaky(y);
    }
}

// ---------------- head: [8,768] @ whead.T + bhead, BN over batch, ReLU -> out [8,7]
__global__ void k_head(const float* __restrict__ hf, const float* __restrict__ wh,
                       const float* __restrict__ bh, const float* __restrict__ g8,
                       const float* __restrict__ b8, float* __restrict__ out) {
    __shared__ float zh[56];
    int t = threadIdx.x;
    if (t < 56) {
        int b = t / 7, o = t % 7;
        float acc = bh[o];
        for (int c = 0; c < 768; ++c) acc += hf[b * 768 + c] * wh[o * 768 + c];
        zh[t] = acc;
    }
    __syncthreads();
    if (t < 7) {
        float s1 = 0.f, s2 = 0.f;
        for (int b = 0; b < NB; ++b) {
            float x = zh[b * 7 + t];
            s1 += x; s2 += x * x;
        }
        float m = s1 * 0.125f, v = s2 * 0.125f - m * m;
        float rs = rsqrtf(v + EPSBN);
        for (int b = 0; b < NB; ++b) {
            float y = g8[t] * (zh[b * 7 + t] - m) * rs + b8[t];
            out[b * 7 + t] = fmaxf(y, 0.f);
        }
    }
}

extern "C" void kernel_launch(void* const* d_in, const int* in_sizes, int n_in, void* d_out,
                              int out_size, void* d_ws, size_t ws_size, hipStream_t stream) {
    const float* x[3] = {(const float*)d_in[0], (const float*)d_in[1], (const float*)d_in[2]};
    const float* w1 = (const float*)d_in[3];
    const float* w2 = (const float*)d_in[4];
    const float* w3 = (const float*)d_in[5];
    const float* w4 = (const float*)d_in[6];
    const float* w5 = (const float*)d_in[7];
    const float* wl1 = (const float*)d_in[8];
    const float* wl2 = (const float*)d_in[9];
    const float* bl2 = (const float*)d_in[10];
    const float* whead = (const float*)d_in[11];
    const float* bhead = (const float*)d_in[12];
    const float *g1 = (const float*)d_in[13], *b1 = (const float*)d_in[14];
    const float *g2 = (const float*)d_in[15], *b2 = (const float*)d_in[16];
    const float *g3 = (const float*)d_in[17], *b3 = (const float*)d_in[18];
    const float *g4 = (const float*)d_in[19], *b4 = (const float*)d_in[20];
    const float *g5 = (const float*)d_in[21], *b5 = (const float*)d_in[22];
    const float *g6 = (const float*)d_in[23], *b6 = (const float*)d_in[24];
    const float *g7 = (const float*)d_in[25], *b7 = (const float*)d_in[26];
    const float *g8 = (const float*)d_in[27], *b8 = (const float*)d_in[28];

    char* w = (char*)d_ws;
    auto alloc = [&](size_t bytes) {
        char* p = w;
        w += (bytes + 255) & ~(size_t)255;
        return p;
    };
    float* xt   = (float*)alloc((size_t)BN * 4 * 4);
    float* xtT  = (float*)alloc((size_t)4 * BN * 4);
    float* hc   = (float*)alloc((size_t)BN * 512 * 4);
    float* hcT  = (float*)alloc((size_t)128 * BN * 4);
    float* gbig = (float*)alloc((size_t)BN * 1024 * 4);  // hmax (<=16MB) then g5 (64MB)
    int*   idx  = (int*)alloc((size_t)BN * KK * 4);
    float* sqv  = (float*)alloc((size_t)BN * 4);
    float* s1g  = (float*)alloc(1024 * 4);
    float* s2g  = (float*)alloc(1024 * 4);
    float* spart = (float*)alloc(2 * SLOTS * 256 * 4);   // conv stats partials (s1|s2)
    float* pmax = (float*)alloc(8 * 1024 * 8 * 4);
    float* psum = (float*)alloc(8 * 1024 * 8 * 4);
    float* pooled = (float*)alloc(8 * 2048 * 4);
    float* z1 = (float*)alloc(8 * 512 * 4);
    float* a1 = (float*)alloc(8 * 512 * 4);
    float* z2 = (float*)alloc(8 * 256 * 4);
    float* hfeat = (float*)alloc(8 * 768 * 4);
    float* Wa1 = (float*)alloc(4 * 64 * 4);
    float* Wd1 = (float*)alloc(4 * 64 * 4);
    float* Wa2 = (float*)alloc(64 * 64 * 4);
    float* Wd2 = (float*)alloc(64 * 64 * 4);
    float* Wa3 = (float*)alloc(64 * 128 * 4);
    float* Wd3 = (float*)alloc(64 * 128 * 4);
    float* Wa4 = (float*)alloc(128 * 256 * 4);
    float* Wd4 = (float*)alloc(128 * 256 * 4);
    float* w5t = (float*)alloc(512 * 1024 * 4);
    float* s1p = spart;
    float* s2p = spart + SLOTS * 256;

    // weight prep (plane-independent)
    k_prepw<<<(4 * 64 + 255) / 256, 256, 0, stream>>>(w1, 64, 3, 4, Wa1, Wd1);
    k_prepw<<<(64 * 64 + 255) / 256, 256, 0, stream>>>(w2, 64, 64, 64, Wa2, Wd2);
    k_prepw<<<(64 * 128 + 255) / 256, 256, 0, stream>>>(w3, 128, 64, 64, Wa3, Wd3);
    k_prepw<<<(128 * 256 + 255) / 256, 256, 0, stream>>>(w4, 256, 128, 128, Wa4, Wd4);
    k_transw5<<<(512 * 1024) / 256, 256, 0, stream>>>(w5, w5t);

    const float inv_e = 1.f / (float)(BN * KK);
    for (int p = 0; p < 3; ++p) {
        k_transpose<<<BN / 256, 256, 0, stream>>>(x[p], xt, xtT);

        // ---- layer 1: F = xt (C=3 padded to 4), O=64 -> hc[:, 0:64]
        k_sq<4><<<BN / 256, 256, 0, stream>>>(xtT, sqv);
        k_knn<4><<<NB * (NP / 8), 256, 0, stream>>>(xtT, sqv, idx);
        hipMemsetAsync(spart, 0, 2 * SLOTS * 256 * 4, stream);
        k_conv<64, 4><<<BN / 2, 64, 0, stream>>>(xt, 4, idx, Wa1, Wd1, gbig, s1p, s2p);
        k_bnmax<<<(BN * 64) / 256, 256, 0, stream>>>(gbig, 64, s1p, s2p, g1, b1, hc, 512, 0, inv_e);
        k_xpose<<<dim3(BN / 64, 1), 256, 0, stream>>>(hc + 0, 512, hcT);

        // ---- layer 2: F = h1 (64), O=64 -> hc[:, 64:128]
        k_sq<64><<<BN / 256, 256, 0, stream>>>(hcT, sqv);
        k_knn<64><<<NB * (NP / 8), 256, 0, stream>>>(hcT, sqv, idx);
        hipMemsetAsync(spart, 0, 2 * SLOTS * 256 * 4, stream);
        k_conv<64, 64><<<BN / 2, 64, 0, stream>>>(hc + 0, 512, idx, Wa2, Wd2, gbig, s1p, s2p);
        k_bnmax<<<(BN * 64) / 256, 256, 0, stream>>>(gbig, 64, s1p, s2p, g2, b2, hc, 512, 64, inv_e);
        k_xpose<<<dim3(BN / 64, 1), 256, 0, stream>>>(hc + 64, 512, hcT);

        // ---- layer 3: F = h2 (64), O=128 -> hc[:, 128:256]
        k_sq<64><<<BN / 256, 256, 0, stream>>>(hcT, sqv);
        k_knn<64><<<NB * (NP / 8), 256, 0, stream>>>(hcT, sqv, idx);
        hipMemsetAsync(spart, 0, 2 * SLOTS * 256 * 4, stream);
        k_conv<128, 64><<<BN / 2, 128, 0, stream>>>(hc + 64, 512, idx, Wa3, Wd3, gbig, s1p, s2p);
        k_bnmax<<<(BN * 128) / 256, 256, 0, stream>>>(gbig, 128, s1p, s2p, g3, b3, hc, 512, 128, inv_e);
        k_xpose<<<dim3(BN / 64, 2), 256, 0, stream>>>(hc + 128, 512, hcT);

        // ---- layer 4: F = h3 (128), O=256 -> hc[:, 256:512]
        k_sq<128><<<BN / 256, 256, 0, stream>>>(hcT, sqv);
        k_knn<128><<<NB * (NP / 8), 256, 0, stream>>>(hcT, sqv, idx);
        hipMemsetAsync(spart, 0, 2 * SLOTS * 256 * 4, stream);
        k_conv<256, 128><<<BN / 2, 256, 0, stream>>>(hc + 128, 512, idx, Wa4, Wd4, gbig, s1p, s2p);
        k_bnmax<<<(BN * 256) / 256, 256, 0, stream>>>(gbig, 256, s1p, s2p, g4, b4, hc, 512, 256, inv_e);

        // ---- w5 + BN + pool
        hipMemsetAsync(s1g, 0, 8192, stream);
        k_w5<<<(BN / 16) * 4, 256, 0, stream>>>(hc, w5t, gbig, s1g, s2g);
        k_pool<<<256, 256, 0, stream>>>(gbig, s1g, s2g, g5, b5, pmax, psum);
        k_poolfin<<<32, 256, 0, stream>>>(pmax, psum, pooled);

        // ---- FC head of the plane
        k_fc<2048><<<(8 * 512 + 255) / 256, 256, 0, stream>>>(pooled, wl1, nullptr, 512, z1);
        k_bnb<<<2, 256, 0, stream>>>(z1, 512, g6, b6, a1, 512, 0);
        k_fc<512><<<(8 * 256 + 255) / 256, 256, 0, stream>>>(a1, wl2, bl2, 256, z2);
        k_bnb<<<1, 256, 0, stream>>>(z2, 256, g7, b7, hfeat, 768, p * 256);
    }
    k_head<<<1, 64, 0, stream>>>(hfeat, whead, bhead, g8, b8, (float*)d_out);
}

// Round 7
// 5461.040 us; speedup vs baseline: 1.6246x; 1.0912x over previous
//
#include <hip/hip_runtime.h>
#include <hip/hip_bf16.h>
#include <cstdint>
#include <cstddef>

constexpr int NB = 8;      // batch
constexpr int NP = 2048;   // points per cloud
constexpr int BN = NB * NP;  // 16384
constexpr int KK = 20;     // neighbors
constexpr float EPSBN = 1e-5f;
constexpr float NEG = -3.402823466e38f;
constexpr int SLOTS = 8;    // fp32 conv1 stats slots
constexpr int SLOTSM = 32;  // mfma conv stats slots
constexpr int SLOTSW = 8;   // w5 stats slots

typedef __attribute__((ext_vector_type(8))) short bf16x8;   // 8 bf16 = 4 VGPRs
typedef __attribute__((ext_vector_type(16))) float f32x16;  // 32x32 MFMA acc

__device__ __forceinline__ float leaky(float x) { return x > 0.f ? x : 0.2f * x; }

__device__ __forceinline__ void split2(float x, unsigned short& h, unsigned short& l) {
    __hip_bfloat16 hh = __float2bfloat16(x);
    float hf = __bfloat162float(hh);
    __hip_bfloat16 ll = __float2bfloat16(x - hf);
    h = *reinterpret_cast<unsigned short*>(&hh);
    l = *reinterpret_cast<unsigned short*>(&ll);
}

__device__ __forceinline__ float b2f(unsigned short u) {
    __hip_bfloat16 h = *reinterpret_cast<__hip_bfloat16*>(&u);
    return __bfloat162float(h);
}

// float -> orderable u32 (ascending uint == ascending float)
__device__ __forceinline__ unsigned int f2key(float f) {
    unsigned int u = __float_as_uint(f);
    return u ^ (unsigned int)(((int)u >> 31) | 0x80000000);
}

// ---------------- transpose x [8,3,2048] -> xt [BN][4] (pad c3=0) and xtT [4][BN]
__global__ void k_transpose(const float* __restrict__ x, float* __restrict__ xt,
                            float* __restrict__ xtT) {
    int i = blockIdx.x * 256 + threadIdx.x;
    if (i >= BN) return;
    int b = i >> 11, n = i & 2047;
    float v0 = x[(b * 3 + 0) * NP + n];
    float v1 = x[(b * 3 + 1) * NP + n];
    float v2 = x[(b * 3 + 2) * NP + n];
    float4 v; v.x = v0; v.y = v1; v.z = v2; v.w = 0.f;
    *(float4*)&xt[(size_t)i * 4] = v;
    xtT[0 * BN + i] = v0;
    xtT[1 * BN + i] = v1;
    xtT[2 * BN + i] = v2;
    xtT[3 * BN + i] = 0.f;
}

// ---------------- sq[i] = |F_i|^2 from transposed features FT [CP][BN]
template <int CP>
__global__ void k_sq(const float* __restrict__ FT, float* __restrict__ sq) {
    int i = blockIdx.x * 256 + threadIdx.x;
    if (i >= BN) return;
    float s = 0.f;
#pragma unroll
    for (int c = 0; c < CP; ++c) {
        float f = FT[(size_t)c * BN + i];
        s += f * f;
    }
    sq[i] = s;
}

// ---------------- knn: top-20 farthest, fp32 distances, radix-descend selection
template <int CP>
__launch_bounds__(256, 2)
__global__ void k_knn(const float* __restrict__ FT, const float* __restrict__ sq,
                      int* __restrict__ gidx) {
    constexpr int R = 8;
    __shared__ unsigned int ds[R][NP];   // 64 KiB of keys
    int t = threadIdx.x;
    int b = blockIdx.x >> 8;
    int n0 = (blockIdx.x & 255) * R;
    const float* FTb = FT + (size_t)b * NP;
    const float* sqb = sq + (size_t)b * NP;

    float acc[R][8];
#pragma unroll
    for (int r = 0; r < R; ++r)
#pragma unroll
        for (int mi = 0; mi < 8; ++mi) acc[r][mi] = 0.f;

    for (int cq = 0; cq < CP / 4; ++cq) {
        float4 c4[R];
#pragma unroll
        for (int r = 0; r < R; ++r) {
            c4[r].x = FTb[(size_t)(cq * 4 + 0) * BN + n0 + r];
            c4[r].y = FTb[(size_t)(cq * 4 + 1) * BN + n0 + r];
            c4[r].z = FTb[(size_t)(cq * 4 + 2) * BN + n0 + r];
            c4[r].w = FTb[(size_t)(cq * 4 + 3) * BN + n0 + r];
        }
#pragma unroll
        for (int mi = 0; mi < 8; ++mi) {
            int m = t + mi * 256;
            float f0 = FTb[(size_t)(cq * 4 + 0) * BN + m];
            float f1 = FTb[(size_t)(cq * 4 + 1) * BN + m];
            float f2 = FTb[(size_t)(cq * 4 + 2) * BN + m];
            float f3 = FTb[(size_t)(cq * 4 + 3) * BN + m];
#pragma unroll
            for (int r = 0; r < R; ++r)
                acc[r][mi] += f0 * c4[r].x + f1 * c4[r].y + f2 * c4[r].z + f3 * c4[r].w;
        }
    }
#pragma unroll
    for (int mi = 0; mi < 8; ++mi) {
        int m = t + mi * 256;
        float sm = sqb[m];
#pragma unroll
        for (int r = 0; r < R; ++r) ds[r][m] = f2key(sm - 2.f * acc[r][mi]);
    }
    __syncthreads();

    int wave = t >> 6, lane = t & 63;
    unsigned long long below = (1ull << lane) - 1ull;
#pragma unroll 1
    for (int rr = 0; rr < 2; ++rr) {
        int r = wave * 2 + rr;
        unsigned int kv[32];
#pragma unroll
        for (int j = 0; j < 32; ++j) kv[j] = ds[r][lane + 64 * j];

        unsigned int T = 0;
#pragma unroll 1
        for (int bit = 31; bit >= 0; --bit) {
            unsigned int tt = T | (1u << bit);
            int c = 0;
#pragma unroll
            for (int j = 0; j < 32; ++j)
                c += (int)__popcll(__ballot(kv[j] >= tt));
            if (c >= KK) T = tt;
        }

        int obase = (b * NP + n0 + r) * KK;
        int base = 0;
#pragma unroll 1
        for (int j = 0; j < 32; ++j) {
            bool pg = kv[j] > T;
            unsigned long long mk = __ballot(pg);
            if (pg) gidx[obase + base + (int)__popcll(mk & below)] = lane + 64 * j;
            base += (int)__popcll(mk);
        }
        int rem = KK - base;
#pragma unroll 1
        for (int j = 0; j < 32; ++j) {
            if (rem <= 0) break;
            bool pe = kv[j] == T;
            unsigned long long mk = __ballot(pe);
            int myp = (int)__popcll(mk & below);
            if (pe && myp < rem) gidx[obase + base + myp] = lane + 64 * j;
            int cnt = (int)__popcll(mk);
            int take = cnt < rem ? cnt : rem;
            base += take; rem -= take;
        }
    }
}

// ---------------- prep (conv1, fp32): W [O][2C] -> WaT [CP][O], WdT [CP][O]
__global__ void k_prepw(const float* __restrict__ W, int O, int Cact, int CP,
                        float* __restrict__ WaT, float* __restrict__ WdT) {
    int i = blockIdx.x * 256 + threadIdx.x;
    if (i >= CP * O) return;
    int c = i / O, o = i % O;
    float wa = (c < Cact) ? W[o * 2 * Cact + c] : 0.f;
    float wb = (c < Cact) ? W[o * 2 * Cact + Cact + c] : 0.f;
    WaT[i] = wa;
    WdT[i] = wb - wa;
}

// ---------------- prep (mfma convs): W [O][2C] fp32 -> split Wa [O][C], Wd=Wb-Wa [O][C]
__global__ void k_prepws(const float* __restrict__ W, int O, int C,
                         unsigned short* __restrict__ WaH, unsigned short* __restrict__ WaL,
                         unsigned short* __restrict__ WdH, unsigned short* __restrict__ WdL) {
    int i = blockIdx.x * 256 + threadIdx.x;
    if (i >= O * C) return;
    int o = i / C, k = i % C;
    float wa = W[o * 2 * C + k];
    float wd = W[o * 2 * C + C + k] - wa;
    split2(wa, WaH[i], WaL[i]);
    split2(wd, WdH[i], WdL[i]);
}

// ---------------- split w5 [1024][512] fp32 -> hi/lo bf16
__global__ void k_splitw5(const float* __restrict__ w5, unsigned short* __restrict__ w5H,
                          unsigned short* __restrict__ w5L) {
    int i = blockIdx.x * 256 + threadIdx.x;
    if (i >= 1024 * 512) return;
    split2(w5[i], w5H[i], w5L[i]);
}

// ---------------- fp32 edge conv (layer 1 only, tiny C)
template <int O, int CP>
__launch_bounds__(O)
__global__ void k_conv(const float* __restrict__ F, int ld, const int* __restrict__ gidx,
                       const float* __restrict__ WaT, const float* __restrict__ WdT,
                       float* __restrict__ hmax, float* __restrict__ s1p,
                       float* __restrict__ s2p) {
    constexpr int CP4 = CP / 4;
    __shared__ float nbrT[2][CP][32];
    __shared__ float sctr[2][CP];
    __shared__ int sidx[2][KK];
    int t = threadIdx.x;
    int p0 = blockIdx.x * 2;
    int b = p0 >> 11;
    const float* Fb = F + (size_t)b * NP * ld;

    if (t < 2 * KK) {
        int pt = t / KK, k = t % KK;
        sidx[pt][k] = gidx[(size_t)(p0 + pt) * KK + k];
    }
    for (int e = t; e < 2 * CP; e += O) {
        int pt = e / CP, cc = e % CP;
        int n = (p0 + pt) & 2047;
        sctr[pt][cc] = Fb[(size_t)n * ld + cc];
    }
    __syncthreads();
    for (int e = t; e < 2 * KK * CP4; e += O) {
        int pt = e / (KK * CP4);
        int e2 = e % (KK * CP4);
        int k = e2 / CP4, cq = e2 % CP4;
        float4 f = *(const float4*)&Fb[(size_t)sidx[pt][k] * ld + cq * 4];
        int kp = (k + 4 * (cq & 7)) & 31;
        nbrT[pt][cq * 4 + 0][kp] = f.x;
        nbrT[pt][cq * 4 + 1][kp] = f.y;
        nbrT[pt][cq * 4 + 2][kp] = f.z;
        nbrT[pt][cq * 4 + 3][kp] = f.w;
    }
    __syncthreads();

    int o = t;
    float bacc0 = 0.f, bacc1 = 0.f;
#pragma unroll 4
    for (int c = 0; c < CP; ++c) {
        float w = WdT[c * O + o];
        bacc0 += sctr[0][c] * w;
        bacc1 += sctr[1][c] * w;
    }
    float a0[KK], a1[KK];
#pragma unroll
    for (int k = 0; k < KK; ++k) { a0[k] = 0.f; a1[k] = 0.f; }
#pragma unroll 2
    for (int c = 0; c < CP; ++c) {
        float w = WaT[c * O + o];
        int s = 4 * ((c >> 2) & 7);
#pragma unroll
        for (int kq = 0; kq < KK / 4; ++kq) {
            int kp = (4 * kq + s) & 31;
            float4 f0 = *(const float4*)&nbrT[0][c][kp];
            float4 f1 = *(const float4*)&nbrT[1][c][kp];
            a0[kq * 4 + 0] += w * f0.x; a1[kq * 4 + 0] += w * f1.x;
            a0[kq * 4 + 1] += w * f0.y; a1[kq * 4 + 1] += w * f1.y;
            a0[kq * 4 + 2] += w * f0.z; a1[kq * 4 + 2] += w * f1.z;
            a0[kq * 4 + 3] += w * f0.w; a1[kq * 4 + 3] += w * f1.w;
        }
    }
    float hm0 = NEG, hm1 = NEG, ts1 = 0.f, ts2 = 0.f;
#pragma unroll
    for (int k = 0; k < KK; ++k) {
        float h0 = a0[k] + bacc0;
        float h1 = a1[k] + bacc1;
        hm0 = fmaxf(hm0, h0); hm1 = fmaxf(hm1, h1);
        ts1 += h0 + h1; ts2 += h0 * h0 + h1 * h1;
    }
    hmax[(size_t)p0 * O + o] = hm0;
    hmax[(size_t)(p0 + 1) * O + o] = hm1;
    int slot = blockIdx.x & (SLOTS - 1);
    atomicAdd(&s1p[slot * O + o], ts1);
    atomicAdd(&s2p[slot * O + o], ts2);
}

// ---------------- dense split GEMM: bacc[BN][O] = hc[:, COFF:COFF+C] @ Wd^T (fp32 out)
template <int O, int C, int COFF>
__launch_bounds__(256)
__global__ void k_gemms(const unsigned short* __restrict__ hcH,
                        const unsigned short* __restrict__ hcL,
                        const unsigned short* __restrict__ WdH,
                        const unsigned short* __restrict__ WdL,
                        float* __restrict__ bacc) {
    constexpr int NT = O / 32, KS = C / 16;
    int tid = threadIdx.x, wave = tid >> 6, lane = tid & 63;
    int row = lane & 31, half = lane >> 5;
    int p0 = blockIdx.x * 128 + wave * 32;
    const unsigned short* aH = hcH + (size_t)(p0 + row) * 512 + COFF;
    const unsigned short* aL = hcL + (size_t)(p0 + row) * 512 + COFF;
    f32x16 acc[NT];
#pragma unroll
    for (int nt = 0; nt < NT; ++nt)
#pragma unroll
        for (int r = 0; r < 16; ++r) acc[nt][r] = 0.f;

#pragma unroll 2
    for (int ks = 0; ks < KS; ++ks) {
        int k0 = ks * 16 + half * 8;
        bf16x8 avh = *(const bf16x8*)(aH + k0);
        bf16x8 avl = *(const bf16x8*)(aL + k0);
#pragma unroll
        for (int nt = 0; nt < NT; ++nt) {
            int j = nt * 32 + row;
            bf16x8 bvh = *(const bf16x8*)(WdH + (size_t)j * C + k0);
            bf16x8 bvl = *(const bf16x8*)(WdL + (size_t)j * C + k0);
            acc[nt] = __builtin_amdgcn_mfma_f32_32x32x16_bf16(avh, bvh, acc[nt], 0, 0, 0);
            acc[nt] = __builtin_amdgcn_mfma_f32_32x32x16_bf16(avh, bvl, acc[nt], 0, 0, 0);
            acc[nt] = __builtin_amdgcn_mfma_f32_32x32x16_bf16(avl, bvh, acc[nt], 0, 0, 0);
        }
    }
#pragma unroll
    for (int nt = 0; nt < NT; ++nt)
#pragma unroll
        for (int r = 0; r < 16; ++r) {
            int i = (r & 3) + 8 * (r >> 2) + 4 * half;
            bacc[(size_t)(p0 + i) * O + nt * 32 + row] = acc[nt][r];
        }
}

// ---------------- MFMA split edge conv: per-wave per-point 32-row GEMM over K=C (nbr only)
// A rows 0-19 = neighbors, 20-31 pad (ignored). Epilogue adds bacc[p][o].
template <int O, int C, int COFF>
__launch_bounds__(256)
__global__ void k_convms(const unsigned short* __restrict__ hcH,
                         const unsigned short* __restrict__ hcL,
                         const int* __restrict__ gidx,
                         const unsigned short* __restrict__ WaH,
                         const unsigned short* __restrict__ WaL,
                         const float* __restrict__ bacc,
                         float* __restrict__ hmax, float* __restrict__ s1p,
                         float* __restrict__ s2p) {
    constexpr int NT = O / 32, KS = C / 16, PPW = 4;
    int tid = threadIdx.x, wave = tid >> 6, lane = tid & 63;
    int row = lane & 31, half = lane >> 5;
    int pbase = (blockIdx.x * 4 + wave) * PPW;
    int b = pbase >> 11;

    float ts1[NT], ts2[NT];
#pragma unroll
    for (int nt = 0; nt < NT; ++nt) { ts1[nt] = 0.f; ts2[nt] = 0.f; }

#pragma unroll 1
    for (int pp = 0; pp < PPW; ++pp) {
        int p = pbase + pp;
        int nidx = gidx[(size_t)p * KK + (row < KK ? row : 0)];
        const unsigned short* aH = hcH + (size_t)(b * 2048 + nidx) * 512 + COFF;
        const unsigned short* aL = hcL + (size_t)(b * 2048 + nidx) * 512 + COFF;
        f32x16 acc[NT];
#pragma unroll
        for (int nt = 0; nt < NT; ++nt)
#pragma unroll
            for (int r = 0; r < 16; ++r) acc[nt][r] = 0.f;

#pragma unroll 2
        for (int ks = 0; ks < KS; ++ks) {
            int k0 = ks * 16 + half * 8;
            bf16x8 avh = *(const bf16x8*)(aH + k0);
            bf16x8 avl = *(const bf16x8*)(aL + k0);
#pragma unroll
            for (int nt = 0; nt < NT; ++nt) {
                int j = nt * 32 + row;
                bf16x8 bvh = *(const bf16x8*)(WaH + (size_t)j * C + k0);
                bf16x8 bvl = *(const bf16x8*)(WaL + (size_t)j * C + k0);
                acc[nt] = __builtin_amdgcn_mfma_f32_32x32x16_bf16(avh, bvh, acc[nt], 0, 0, 0);
                acc[nt] = __builtin_amdgcn_mfma_f32_32x32x16_bf16(avh, bvl, acc[nt], 0, 0, 0);
                acc[nt] = __builtin_amdgcn_mfma_f32_32x32x16_bf16(avl, bvh, acc[nt], 0, 0, 0);
            }
        }
        // epilogue: D row i = (r&3)+8*(r>>2)+4*half, col = nt*32 + row; h = D + bacc[p][col]
#pragma unroll
        for (int nt = 0; nt < NT; ++nt) {
            float bf = bacc[(size_t)p * O + nt * 32 + row];
            float mx = NEG;
#pragma unroll
            for (int r = 0; r < 16; ++r) {
                int i = (r & 3) + 8 * (r >> 2) + 4 * half;
                if (i < KK) {
                    float v = acc[nt][r] + bf;
                    mx = fmaxf(mx, v);
                    ts1[nt] += v; ts2[nt] += v * v;
                }
            }
            float mo = __shfl_xor(mx, 32);
            mx = fmaxf(mx, mo);
            if (half == 0) hmax[(size_t)p * O + nt * 32 + row] = mx;
        }
    }
    int slot = blockIdx.x & (SLOTSM - 1);
#pragma unroll
    for (int nt = 0; nt < NT; ++nt) {
        float a1 = ts1[nt] + __shfl_xor(ts1[nt], 32);
        float a2 = ts2[nt] + __shfl_xor(ts2[nt], 32);
        if (half == 0) {
            atomicAdd(&s1p[slot * O + nt * 32 + row], a1);
            atomicAdd(&s2p[slot * O + nt * 32 + row], a2);
        }
    }
}

// ---------------- reduce slotted stats -> s1g/s2g
__global__ void k_redslots(const float* __restrict__ s1p, const float* __restrict__ s2p,
                           int O, int S, float* __restrict__ s1g, float* __restrict__ s2g) {
    int o = blockIdx.x * 256 + threadIdx.x;
    if (o >= O) return;
    float a = 0.f, c = 0.f;
    for (int s = 0; s < S; ++s) { a += s1p[s * O + o]; c += s2p[s * O + o]; }
    s1g[o] = a; s2g[o] = c;
}

// ---------------- BN(+leaky) on per-point max; writes split hi/lo bf16
__global__ void k_bnmax(const float* __restrict__ hmax, int O, const float* __restrict__ s1g,
                        const float* __restrict__ s2g, const float* __restrict__ gam,
                        const float* __restrict__ bet, unsigned short* __restrict__ outH,
                        unsigned short* __restrict__ outL, int ostride, int ooff,
                        float inv_cnt) {
    int i = blockIdx.x * 256 + threadIdx.x;
    if (i >= BN * O) return;
    int o = i % O, p = i / O;
    float m = s1g[o] * inv_cnt;
    float v = s2g[o] * inv_cnt - m * m;
    float rs = rsqrtf(v + EPSBN);
    float y = leaky(gam[o] * (hmax[i] - m) * rs + bet[o]);
    size_t oi = (size_t)p * ostride + ooff + o;
    split2(y, outH[oi], outL[oi]);
}

// ---------------- tiled transpose from hi/lo bf16: cols [coff+o0, ...) -> hcT [O][BN] fp32
__global__ void k_xposeB(const unsigned short* __restrict__ inH,
                         const unsigned short* __restrict__ inL, int coff,
                         float* __restrict__ out) {
    __shared__ float tile[64][65];
    int tx = threadIdx.x & 63, ty = threadIdx.x >> 6;
    int p0 = blockIdx.x * 64, o0 = blockIdx.y * 64;
    for (int i = ty; i < 64; i += 4) {
        size_t idx = (size_t)(p0 + i) * 512 + coff + o0 + tx;
        tile[i][tx] = b2f(inH[idx]) + b2f(inL[idx]);
    }
    __syncthreads();
    for (int i = ty; i < 64; i += 4)
        out[(size_t)(o0 + i) * BN + p0 + tx] = tile[tx][i];
}

// ---------------- w5 split GEMM: g5 = hc[BN][512] @ w5^T -> [BN][1024] + stats
__launch_bounds__(256)
__global__ void k_w5ms(const unsigned short* __restrict__ hcH,
                       const unsigned short* __restrict__ hcL,
                       const unsigned short* __restrict__ w5H,
                       const unsigned short* __restrict__ w5L,
                       float* __restrict__ g5, float* __restrict__ s1p,
                       float* __restrict__ s2p) {
    int tid = threadIdx.x, wave = tid >> 6, lane = tid & 63;
    int row = lane & 31, half = lane >> 5;
    int p0 = blockIdx.x * 32;
    const unsigned short* aH = hcH + (size_t)(p0 + row) * 512;
    const unsigned short* aL = hcL + (size_t)(p0 + row) * 512;
    f32x16 acc[8];
#pragma unroll
    for (int nt = 0; nt < 8; ++nt)
#pragma unroll
        for (int r = 0; r < 16; ++r) acc[nt][r] = 0.f;

#pragma unroll 1
    for (int ks = 0; ks < 32; ++ks) {
        int k0 = ks * 16 + half * 8;
        bf16x8 avh = *(const bf16x8*)(aH + k0);
        bf16x8 avl = *(const bf16x8*)(aL + k0);
#pragma unroll
        for (int nt = 0; nt < 8; ++nt) {
            int j = wave * 256 + nt * 32 + row;
            bf16x8 bvh = *(const bf16x8*)(w5H + (size_t)j * 512 + k0);
            bf16x8 bvl = *(const bf16x8*)(w5L + (size_t)j * 512 + k0);
            acc[nt] = __builtin_amdgcn_mfma_f32_32x32x16_bf16(avh, bvh, acc[nt], 0, 0, 0);
            acc[nt] = __builtin_amdgcn_mfma_f32_32x32x16_bf16(avh, bvl, acc[nt], 0, 0, 0);
            acc[nt] = __builtin_amdgcn_mfma_f32_32x32x16_bf16(avl, bvh, acc[nt], 0, 0, 0);
        }
    }
    int slot = blockIdx.x & (SLOTSW - 1);
#pragma unroll
    for (int nt = 0; nt < 8; ++nt) {
        int j = wave * 256 + nt * 32 + row;
        float s1 = 0.f, s2 = 0.f;
#pragma unroll
        for (int r = 0; r < 16; ++r) {
            int i = (r & 3) + 8 * (r >> 2) + 4 * half;
            float v = acc[nt][r];
            g5[(size_t)(p0 + i) * 1024 + j] = v;
            s1 += v; s2 += v * v;
        }
        s1 += __shfl_xor(s1, 32);
        s2 += __shfl_xor(s2, 32);
        if (half == 0) {
            atomicAdd(&s1p[slot * 1024 + j], s1);
            atomicAdd(&s2p[slot * 1024 + j], s2);
        }
    }
}

// ---------------- pool: per (b, o-tile, n-chunk) partial max / partial sum
__global__ void k_pool(const float* __restrict__ gbuf, const float* __restrict__ s1g,
                       const float* __restrict__ s2g, const float* __restrict__ gam,
                       const float* __restrict__ bet, float* __restrict__ pmax,
                       float* __restrict__ psum) {
    int t = threadIdx.x;
    int blk = blockIdx.x;
    int nc = blk & 7, ot = (blk >> 3) & 3, b = blk >> 5;
    int o = ot * 256 + t;
    float m = s1g[o] * (1.f / 16384.f);
    float v = s2g[o] * (1.f / 16384.f) - m * m;
    float rs = rsqrtf(v + EPSBN);
    float ga = gam[o], be = bet[o];
    float vmax = NEG, vsum = 0.f;
    for (int j = 0; j < 256; ++j) {
        int n = nc * 256 + j;
        float x = gbuf[((size_t)b * NP + n) * 1024 + o];
        float y = leaky(ga * (x - m) * rs + be);
        vmax = fmaxf(vmax, y);
        vsum += y;
    }
    pmax[(b * 1024 + o) * 8 + nc] = vmax;
    psum[(b * 1024 + o) * 8 + nc] = vsum;
}

__global__ void k_poolfin(const float* __restrict__ pmax, const float* __restrict__ psum,
                          float* __restrict__ pooled) {
    int i = blockIdx.x * 256 + threadIdx.x;
    if (i >= 8192) return;
    float mx = NEG, sm = 0.f;
    for (int j = 0; j < 8; ++j) {
        mx = fmaxf(mx, pmax[i * 8 + j]);
        sm += psum[i * 8 + j];
    }
    int b = i >> 10, o = i & 1023;
    pooled[b * 2048 + o] = mx;
    pooled[b * 2048 + 1024 + o] = sm * (1.f / 2048.f);
}

// ---------------- small FC: z[b][o] = in[b] . W[o] (+bias)
template <int CIN>
__global__ void k_fc(const float* __restrict__ in, const float* __restrict__ W,
                     const float* __restrict__ bias, int O, float* __restrict__ z) {
    int i = blockIdx.x * 256 + threadIdx.x;
    if (i >= NB * O) return;
    int b = i / O, o = i % O;
    const float* wr = W + (size_t)o * CIN;
    const float* ir = in + (size_t)b * CIN;
    float acc = 0.f;
#pragma unroll 4
    for (int cq = 0; cq < CIN / 4; ++cq) {
        float4 wv = *(const float4*)&wr[cq * 4];
        float4 iv = *(const float4*)&ir[cq * 4];
        acc += wv.x * iv.x + wv.y * iv.y + wv.z * iv.z + wv.w * iv.w;
    }
    z[i] = acc + (bias ? bias[o] : 0.f);
}

// ---------------- BN over batch (8 samples) + leaky
__global__ void k_bnb(const float* __restrict__ z, int O, const float* __restrict__ gam,
                      const float* __restrict__ bet, float* __restrict__ out, int ostride,
                      int ooff) {
    int o = blockIdx.x * 256 + threadIdx.x;
    if (o >= O) return;
    float s1 = 0.f, s2 = 0.f;
#pragma unroll
    for (int b = 0; b < NB; ++b) {
        float x = z[b * O + o];
        s1 += x; s2 += x * x;
    }
    float m = s1 * 0.125f, v = s2 * 0.125f - m * m;
    float rs = rsqrtf(v + EPSBN);
    float ga = gam[o], be = bet[o];
    for (int b = 0; b < NB; ++b) {
        float y = ga * (z[b * O + o] - m) * rs + be;
        out[b * ostride + ooff + o] = leaky(y);
    }
}

// ---------------- head
__global__ void k_head(const float* __restrict__ hf, const float* __restrict__ wh,
                       const float* __restrict__ bh, const float* __restrict__ g8,
                       const float* __restrict__ b8, float* __restrict__ out) {
    __shared__ float zh[56];
    int t = threadIdx.x;
    if (t < 56) {
        int b = t / 7, o = t % 7;
        float acc = bh[o];
        for (int c = 0; c < 768; ++c) acc += hf[b * 768 + c] * wh[o * 768 + c];
        zh[t] = acc;
    }
    __syncthreads();
    if (t < 7) {
        float s1 = 0.f, s2 = 0.f;
        for (int b = 0; b < NB; ++b) {
            float x = zh[b * 7 + t];
            s1 += x; s2 += x * x;
        }
        float m = s1 * 0.125f, v = s2 * 0.125f - m * m;
        float rs = rsqrtf(v + EPSBN);
        for (int b = 0; b < NB; ++b) {
            float y = g8[t] * (zh[b * 7 + t] - m) * rs + b8[t];
            out[b * 7 + t] = fmaxf(y, 0.f);
        }
    }
}

extern "C" void kernel_launch(void* const* d_in, const int* in_sizes, int n_in, void* d_out,
                              int out_size, void* d_ws, size_t ws_size, hipStream_t stream) {
    const float* x[3] = {(const float*)d_in[0], (const float*)d_in[1], (const float*)d_in[2]};
    const float* w1 = (const float*)d_in[3];
    const float* w2 = (const float*)d_in[4];
    const float* w3 = (const float*)d_in[5];
    const float* w4 = (const float*)d_in[6];
    const float* w5 = (const float*)d_in[7];
    const float* wl1 = (const float*)d_in[8];
    const float* wl2 = (const float*)d_in[9];
    const float* bl2 = (const float*)d_in[10];
    const float* whead = (const float*)d_in[11];
    const float* bhead = (const float*)d_in[12];
    const float *g1 = (const float*)d_in[13], *b1 = (const float*)d_in[14];
    const float *g2 = (const float*)d_in[15], *b2 = (const float*)d_in[16];
    const float *g3 = (const float*)d_in[17], *b3 = (const float*)d_in[18];
    const float *g4 = (const float*)d_in[19], *b4 = (const float*)d_in[20];
    const float *g5 = (const float*)d_in[21], *b5 = (const float*)d_in[22];
    const float *g6 = (const float*)d_in[23], *b6 = (const float*)d_in[24];
    const float *g7 = (const float*)d_in[25], *b7 = (const float*)d_in[26];
    const float *g8 = (const float*)d_in[27], *b8 = (const float*)d_in[28];

    char* w = (char*)d_ws;
    auto alloc = [&](size_t bytes) {
        char* p = w;
        w += (bytes + 255) & ~(size_t)255;
        return p;
    };
    float* xt   = (float*)alloc((size_t)BN * 4 * 4);
    float* xtT  = (float*)alloc((size_t)4 * BN * 4);
    unsigned short* hcH = (unsigned short*)alloc((size_t)BN * 512 * 2);
    unsigned short* hcL = (unsigned short*)alloc((size_t)BN * 512 * 2);
    float* hcT  = (float*)alloc((size_t)128 * BN * 4);
    float* gbig = (float*)alloc((size_t)BN * 1024 * 4);  // hmax[0,BN*256) | bacc@BN*512 | g5 full
    int*   idx  = (int*)alloc((size_t)BN * KK * 4);
    float* sqv  = (float*)alloc((size_t)BN * 4);
    float* s1g  = (float*)alloc(1024 * 4);
    float* s2g  = (float*)alloc(1024 * 4);
    float* spart  = (float*)alloc(2 * SLOTS * 256 * 4);     // conv1 fp32 stats
    float* spartC = (float*)alloc(2 * SLOTSM * 256 * 4);    // mfma conv stats
    float* spartW = (float*)alloc(2 * SLOTSW * 1024 * 4);   // w5 stats
    float* pmax = (float*)alloc(8 * 1024 * 8 * 4);
    float* psum = (float*)alloc(8 * 1024 * 8 * 4);
    float* pooled = (float*)alloc(8 * 2048 * 4);
    float* z1 = (float*)alloc(8 * 512 * 4);
    float* a1 = (float*)alloc(8 * 512 * 4);
    float* z2 = (float*)alloc(8 * 256 * 4);
    float* hfeat = (float*)alloc(8 * 768 * 4);
    float* Wa1 = (float*)alloc(4 * 64 * 4);
    float* Wd1 = (float*)alloc(4 * 64 * 4);
    unsigned short* WaH2 = (unsigned short*)alloc(64 * 64 * 2);
    unsigned short* WaL2 = (unsigned short*)alloc(64 * 64 * 2);
    unsigned short* WdH2 = (unsigned short*)alloc(64 * 64 * 2);
    unsigned short* WdL2 = (unsigned short*)alloc(64 * 64 * 2);
    unsigned short* WaH3 = (unsigned short*)alloc(128 * 64 * 2);
    unsigned short* WaL3 = (unsigned short*)alloc(128 * 64 * 2);
    unsigned short* WdH3 = (unsigned short*)alloc(128 * 64 * 2);
    unsigned short* WdL3 = (unsigned short*)alloc(128 * 64 * 2);
    unsigned short* WaH4 = (unsigned short*)alloc(256 * 128 * 2);
    unsigned short* WaL4 = (unsigned short*)alloc(256 * 128 * 2);
    unsigned short* WdH4 = (unsigned short*)alloc(256 * 128 * 2);
    unsigned short* WdL4 = (unsigned short*)alloc(256 * 128 * 2);
    unsigned short* w5H  = (unsigned short*)alloc(1024 * 512 * 2);
    unsigned short* w5L  = (unsigned short*)alloc(1024 * 512 * 2);
    float* s1p = spart;
    float* s2p = spart + SLOTS * 256;
    float* s1pc = spartC;
    float* s2pc = spartC + SLOTSM * 256;
    float* s1pw = spartW;
    float* s2pw = spartW + SLOTSW * 1024;
    float* baccP = gbig + (size_t)BN * 512;   // aliased: disjoint from hmax region

    // weight prep (plane-independent)
    k_prepw<<<(4 * 64 + 255) / 256, 256, 0, stream>>>(w1, 64, 3, 4, Wa1, Wd1);
    k_prepws<<<(64 * 64 + 255) / 256, 256, 0, stream>>>(w2, 64, 64, WaH2, WaL2, WdH2, WdL2);
    k_prepws<<<(128 * 64 + 255) / 256, 256, 0, stream>>>(w3, 128, 64, WaH3, WaL3, WdH3, WdL3);
    k_prepws<<<(256 * 128 + 255) / 256, 256, 0, stream>>>(w4, 256, 128, WaH4, WaL4, WdH4, WdL4);
    k_splitw5<<<(1024 * 512) / 256, 256, 0, stream>>>(w5, w5H, w5L);

    const float inv_e = 1.f / (float)(BN * KK);
    for (int p = 0; p < 3; ++p) {
        k_transpose<<<BN / 256, 256, 0, stream>>>(x[p], xt, xtT);

        // ---- layer 1 (fp32): C=3 pad 4, O=64 -> cols 0:64
        k_sq<4><<<BN / 256, 256, 0, stream>>>(xtT, sqv);
        k_knn<4><<<NB * (NP / 8), 256, 0, stream>>>(xtT, sqv, idx);
        hipMemsetAsync(spart, 0, 2 * SLOTS * 256 * 4, stream);
        k_conv<64, 4><<<BN / 2, 64, 0, stream>>>(xt, 4, idx, Wa1, Wd1, gbig, s1p, s2p);
        k_redslots<<<1, 256, 0, stream>>>(s1p, s2p, 64, SLOTS, s1g, s2g);
        k_bnmax<<<(BN * 64) / 256, 256, 0, stream>>>(gbig, 64, s1g, s2g, g1, b1, hcH, hcL, 512, 0, inv_e);
        k_xposeB<<<dim3(BN / 64, 1), 256, 0, stream>>>(hcH, hcL, 0, hcT);

        // ---- layer 2 (mfma split): C=64 @ cols 0:64, O=64 -> cols 64:128
        k_sq<64><<<BN / 256, 256, 0, stream>>>(hcT, sqv);
        k_knn<64><<<NB * (NP / 8), 256, 0, stream>>>(hcT, sqv, idx);
        k_gemms<64, 64, 0><<<BN / 128, 256, 0, stream>>>(hcH, hcL, WdH2, WdL2, baccP);
        hipMemsetAsync(spartC, 0, 2 * SLOTSM * 256 * 4, stream);
        k_convms<64, 64, 0><<<BN / 16, 256, 0, stream>>>(hcH, hcL, idx, WaH2, WaL2, baccP, gbig, s1pc, s2pc);
        k_redslots<<<1, 256, 0, stream>>>(s1pc, s2pc, 64, SLOTSM, s1g, s2g);
        k_bnmax<<<(BN * 64) / 256, 256, 0, stream>>>(gbig, 64, s1g, s2g, g2, b2, hcH, hcL, 512, 64, inv_e);
        k_xposeB<<<dim3(BN / 64, 1), 256, 0, stream>>>(hcH, hcL, 64, hcT);

        // ---- layer 3 (mfma split): C=64 @ cols 64:128, O=128 -> cols 128:256
        k_sq<64><<<BN / 256, 256, 0, stream>>>(hcT, sqv);
        k_knn<64><<<NB * (NP / 8), 256, 0, stream>>>(hcT, sqv, idx);
        k_gemms<128, 64, 64><<<BN / 128, 256, 0, stream>>>(hcH, hcL, WdH3, WdL3, baccP);
        hipMemsetAsync(spartC, 0, 2 * SLOTSM * 256 * 4, stream);
        k_convms<128, 64, 64><<<BN / 16, 256, 0, stream>>>(hcH, hcL, idx, WaH3, WaL3, baccP, gbig, s1pc, s2pc);
        k_redslots<<<1, 256, 0, stream>>>(s1pc, s2pc, 128, SLOTSM, s1g, s2g);
        k_bnmax<<<(BN * 128) / 256, 256, 0, stream>>>(gbig, 128, s1g, s2g, g3, b3, hcH, hcL, 512, 128, inv_e);
        k_xposeB<<<dim3(BN / 64, 2), 256, 0, stream>>>(hcH, hcL, 128, hcT);

        // ---- layer 4 (mfma split): C=128 @ cols 128:256, O=256 -> cols 256:512
        k_sq<128><<<BN / 256, 256, 0, stream>>>(hcT, sqv);
        k_knn<128><<<NB * (NP / 8), 256, 0, stream>>>(hcT, sqv, idx);
        k_gemms<256, 128, 128><<<BN / 128, 256, 0, stream>>>(hcH, hcL, WdH4, WdL4, baccP);
        hipMemsetAsync(spartC, 0, 2 * SLOTSM * 256 * 4, stream);
        k_convms<256, 128, 128><<<BN / 16, 256, 0, stream>>>(hcH, hcL, idx, WaH4, WaL4, baccP, gbig, s1pc, s2pc);
        k_redslots<<<1, 256, 0, stream>>>(s1pc, s2pc, 256, SLOTSM, s1g, s2g);
        k_bnmax<<<(BN * 256) / 256, 256, 0, stream>>>(gbig, 256, s1g, s2g, g4, b4, hcH, hcL, 512, 256, inv_e);

        // ---- w5 (mfma split) + BN + pool
        hipMemsetAsync(spartW, 0, 2 * SLOTSW * 1024 * 4, stream);
        k_w5ms<<<BN / 32, 256, 0, stream>>>(hcH, hcL, w5H, w5L, gbig, s1pw, s2pw);
        k_redslots<<<4, 256, 0, stream>>>(s1pw, s2pw, 1024, SLOTSW, s1g, s2g);
        k_pool<<<256, 256, 0, stream>>>(gbig, s1g, s2g, g5, b5, pmax, psum);
        k_poolfin<<<32, 256, 0, stream>>>(pmax, psum, pooled);

        // ---- FC head of the plane
        k_fc<2048><<<(8 * 512 + 255) / 256, 256, 0, stream>>>(pooled, wl1, nullptr, 512, z1);
        k_bnb<<<2, 256, 0, stream>>>(z1, 512, g6, b6, a1, 512, 0);
        k_fc<512><<<(8 * 256 + 255) / 256, 256, 0, stream>>>(a1, wl2, bl2, 256, z2);
        k_bnb<<<1, 256, 0, stream>>>(z2, 256, g7, b7, hfeat, 768, p * 256);
    }
    k_head<<<1, 64, 0, stream>>>(hfeat, whead, bhead, g8, b8, (float*)d_out);
}

// Round 8
// 5340.996 us; speedup vs baseline: 1.6612x; 1.0225x over previous
//
#include <hip/hip_runtime.h>
#include <hip/hip_bf16.h>
#include <cstdint>
#include <cstddef>

constexpr int NB = 8;      // batch
constexpr int NP = 2048;   // points per cloud
constexpr int BN = NB * NP;  // 16384
constexpr int KK = 20;     // neighbors
constexpr float EPSBN = 1e-5f;
constexpr float NEG = -3.402823466e38f;
constexpr int SLOTS = 8;    // fp32 conv1 stats slots
constexpr int SLOTSM = 32;  // mfma conv stats slots
constexpr int SLOTSW = 8;   // w5 stats slots

typedef __attribute__((ext_vector_type(8))) short bf16x8;   // 8 bf16 = 4 VGPRs
typedef __attribute__((ext_vector_type(16))) float f32x16;  // 32x32 MFMA acc

__device__ __forceinline__ float leaky(float x) { return x > 0.f ? x : 0.2f * x; }

__device__ __forceinline__ void split2(float x, unsigned short& h, unsigned short& l) {
    __hip_bfloat16 hh = __float2bfloat16(x);
    float hf = __bfloat162float(hh);
    __hip_bfloat16 ll = __float2bfloat16(x - hf);
    h = *reinterpret_cast<unsigned short*>(&hh);
    l = *reinterpret_cast<unsigned short*>(&ll);
}

__device__ __forceinline__ float b2f(unsigned short u) {
    __hip_bfloat16 h = *reinterpret_cast<__hip_bfloat16*>(&u);
    return __bfloat162float(h);
}

// float -> orderable u32 (ascending uint == ascending float)
__device__ __forceinline__ unsigned int f2key(float f) {
    unsigned int u = __float_as_uint(f);
    return u ^ (unsigned int)(((int)u >> 31) | 0x80000000);
}

// ---------------- transpose x [8,3,2048] -> xt [BN][4] (pad c3=0) and xtT [4][BN]
__global__ void k_transpose(const float* __restrict__ x, float* __restrict__ xt,
                            float* __restrict__ xtT) {
    int i = blockIdx.x * 256 + threadIdx.x;
    if (i >= BN) return;
    int b = i >> 11, n = i & 2047;
    float v0 = x[(b * 3 + 0) * NP + n];
    float v1 = x[(b * 3 + 1) * NP + n];
    float v2 = x[(b * 3 + 2) * NP + n];
    float4 v; v.x = v0; v.y = v1; v.z = v2; v.w = 0.f;
    *(float4*)&xt[(size_t)i * 4] = v;
    xtT[0 * BN + i] = v0;
    xtT[1 * BN + i] = v1;
    xtT[2 * BN + i] = v2;
    xtT[3 * BN + i] = 0.f;
}

// ---------------- sq[i] = |F_i|^2 from transposed features FT [CP][BN]
template <int CP>
__global__ void k_sq(const float* __restrict__ FT, float* __restrict__ sq) {
    int i = blockIdx.x * 256 + threadIdx.x;
    if (i >= BN) return;
    float s = 0.f;
#pragma unroll
    for (int c = 0; c < CP; ++c) {
        float f = FT[(size_t)c * BN + i];
        s += f * f;
    }
    sq[i] = s;
}

// ---------------- knn: top-20 farthest, fp32 distances, radix-descend selection
template <int CP>
__launch_bounds__(256, 2)
__global__ void k_knn(const float* __restrict__ FT, const float* __restrict__ sq,
                      int* __restrict__ gidx) {
    constexpr int R = 8;
    __shared__ unsigned int ds[R][NP];   // 64 KiB of keys
    int t = threadIdx.x;
    int b = blockIdx.x >> 8;
    int n0 = (blockIdx.x & 255) * R;
    const float* FTb = FT + (size_t)b * NP;
    const float* sqb = sq + (size_t)b * NP;

    float acc[R][8];
#pragma unroll
    for (int r = 0; r < R; ++r)
#pragma unroll
        for (int mi = 0; mi < 8; ++mi) acc[r][mi] = 0.f;

    for (int cq = 0; cq < CP / 4; ++cq) {
        float4 c4[R];
#pragma unroll
        for (int r = 0; r < R; ++r) {
            c4[r].x = FTb[(size_t)(cq * 4 + 0) * BN + n0 + r];
            c4[r].y = FTb[(size_t)(cq * 4 + 1) * BN + n0 + r];
            c4[r].z = FTb[(size_t)(cq * 4 + 2) * BN + n0 + r];
            c4[r].w = FTb[(size_t)(cq * 4 + 3) * BN + n0 + r];
        }
#pragma unroll
        for (int mi = 0; mi < 8; ++mi) {
            int m = t + mi * 256;
            float f0 = FTb[(size_t)(cq * 4 + 0) * BN + m];
            float f1 = FTb[(size_t)(cq * 4 + 1) * BN + m];
            float f2 = FTb[(size_t)(cq * 4 + 2) * BN + m];
            float f3 = FTb[(size_t)(cq * 4 + 3) * BN + m];
#pragma unroll
            for (int r = 0; r < R; ++r)
                acc[r][mi] += f0 * c4[r].x + f1 * c4[r].y + f2 * c4[r].z + f3 * c4[r].w;
        }
    }
#pragma unroll
    for (int mi = 0; mi < 8; ++mi) {
        int m = t + mi * 256;
        float sm = sqb[m];
#pragma unroll
        for (int r = 0; r < R; ++r) ds[r][m] = f2key(sm - 2.f * acc[r][mi]);
    }
    __syncthreads();

    int wave = t >> 6, lane = t & 63;
    unsigned long long below = (1ull << lane) - 1ull;
#pragma unroll 1
    for (int rr = 0; rr < 2; ++rr) {
        int r = wave * 2 + rr;
        unsigned int kv[32];
#pragma unroll
        for (int j = 0; j < 32; ++j) kv[j] = ds[r][lane + 64 * j];

        unsigned int T = 0;
#pragma unroll 1
        for (int bit = 31; bit >= 0; --bit) {
            unsigned int tt = T | (1u << bit);
            int c = 0;
#pragma unroll
            for (int j = 0; j < 32; ++j)
                c += (int)__popcll(__ballot(kv[j] >= tt));
            if (c >= KK) T = tt;
        }

        int obase = (b * NP + n0 + r) * KK;
        int base = 0;
#pragma unroll 1
        for (int j = 0; j < 32; ++j) {
            bool pg = kv[j] > T;
            unsigned long long mk = __ballot(pg);
            if (pg) gidx[obase + base + (int)__popcll(mk & below)] = lane + 64 * j;
            base += (int)__popcll(mk);
        }
        int rem = KK - base;
#pragma unroll 1
        for (int j = 0; j < 32; ++j) {
            if (rem <= 0) break;
            bool pe = kv[j] == T;
            unsigned long long mk = __ballot(pe);
            int myp = (int)__popcll(mk & below);
            if (pe && myp < rem) gidx[obase + base + myp] = lane + 64 * j;
            int cnt = (int)__popcll(mk);
            int take = cnt < rem ? cnt : rem;
            base += take; rem -= take;
        }
    }
}

// ---------------- prep (conv1, fp32): W [O][2C] -> WaT [CP][O], WdT [CP][O]
__global__ void k_prepw(const float* __restrict__ W, int O, int Cact, int CP,
                        float* __restrict__ WaT, float* __restrict__ WdT) {
    int i = blockIdx.x * 256 + threadIdx.x;
    if (i >= CP * O) return;
    int c = i / O, o = i % O;
    float wa = (c < Cact) ? W[o * 2 * Cact + c] : 0.f;
    float wb = (c < Cact) ? W[o * 2 * Cact + Cact + c] : 0.f;
    WaT[i] = wa;
    WdT[i] = wb - wa;
}

// ---------------- prep (mfma convs): W [O][2C] fp32 -> split Wa [O][C], Wd=Wb-Wa [O][C]
__global__ void k_prepws(const float* __restrict__ W, int O, int C,
                         unsigned short* __restrict__ WaH, unsigned short* __restrict__ WaL,
                         unsigned short* __restrict__ WdH, unsigned short* __restrict__ WdL) {
    int i = blockIdx.x * 256 + threadIdx.x;
    if (i >= O * C) return;
    int o = i / C, k = i % C;
    float wa = W[o * 2 * C + k];
    float wd = W[o * 2 * C + C + k] - wa;
    split2(wa, WaH[i], WaL[i]);
    split2(wd, WdH[i], WdL[i]);
}

// ---------------- split w5 [1024][512] fp32 -> hi/lo bf16
__global__ void k_splitw5(const float* __restrict__ w5, unsigned short* __restrict__ w5H,
                          unsigned short* __restrict__ w5L) {
    int i = blockIdx.x * 256 + threadIdx.x;
    if (i >= 1024 * 512) return;
    split2(w5[i], w5H[i], w5L[i]);
}

// ---------------- fp32 edge conv (layer 1 only, tiny C)
template <int O, int CP>
__launch_bounds__(O)
__global__ void k_conv(const float* __restrict__ F, int ld, const int* __restrict__ gidx,
                       const float* __restrict__ WaT, const float* __restrict__ WdT,
                       float* __restrict__ hmax, float* __restrict__ s1p,
                       float* __restrict__ s2p) {
    constexpr int CP4 = CP / 4;
    __shared__ float nbrT[2][CP][32];
    __shared__ float sctr[2][CP];
    __shared__ int sidx[2][KK];
    int t = threadIdx.x;
    int p0 = blockIdx.x * 2;
    int b = p0 >> 11;
    const float* Fb = F + (size_t)b * NP * ld;

    if (t < 2 * KK) {
        int pt = t / KK, k = t % KK;
        sidx[pt][k] = gidx[(size_t)(p0 + pt) * KK + k];
    }
    for (int e = t; e < 2 * CP; e += O) {
        int pt = e / CP, cc = e % CP;
        int n = (p0 + pt) & 2047;
        sctr[pt][cc] = Fb[(size_t)n * ld + cc];
    }
    __syncthreads();
    for (int e = t; e < 2 * KK * CP4; e += O) {
        int pt = e / (KK * CP4);
        int e2 = e % (KK * CP4);
        int k = e2 / CP4, cq = e2 % CP4;
        float4 f = *(const float4*)&Fb[(size_t)sidx[pt][k] * ld + cq * 4];
        int kp = (k + 4 * (cq & 7)) & 31;
        nbrT[pt][cq * 4 + 0][kp] = f.x;
        nbrT[pt][cq * 4 + 1][kp] = f.y;
        nbrT[pt][cq * 4 + 2][kp] = f.z;
        nbrT[pt][cq * 4 + 3][kp] = f.w;
    }
    __syncthreads();

    int o = t;
    float bacc0 = 0.f, bacc1 = 0.f;
#pragma unroll 4
    for (int c = 0; c < CP; ++c) {
        float w = WdT[c * O + o];
        bacc0 += sctr[0][c] * w;
        bacc1 += sctr[1][c] * w;
    }
    float a0[KK], a1[KK];
#pragma unroll
    for (int k = 0; k < KK; ++k) { a0[k] = 0.f; a1[k] = 0.f; }
#pragma unroll 2
    for (int c = 0; c < CP; ++c) {
        float w = WaT[c * O + o];
        int s = 4 * ((c >> 2) & 7);
#pragma unroll
        for (int kq = 0; kq < KK / 4; ++kq) {
            int kp = (4 * kq + s) & 31;
            float4 f0 = *(const float4*)&nbrT[0][c][kp];
            float4 f1 = *(const float4*)&nbrT[1][c][kp];
            a0[kq * 4 + 0] += w * f0.x; a1[kq * 4 + 0] += w * f1.x;
            a0[kq * 4 + 1] += w * f0.y; a1[kq * 4 + 1] += w * f1.y;
            a0[kq * 4 + 2] += w * f0.z; a1[kq * 4 + 2] += w * f1.z;
            a0[kq * 4 + 3] += w * f0.w; a1[kq * 4 + 3] += w * f1.w;
        }
    }
    float hm0 = NEG, hm1 = NEG, ts1 = 0.f, ts2 = 0.f;
#pragma unroll
    for (int k = 0; k < KK; ++k) {
        float h0 = a0[k] + bacc0;
        float h1 = a1[k] + bacc1;
        hm0 = fmaxf(hm0, h0); hm1 = fmaxf(hm1, h1);
        ts1 += h0 + h1; ts2 += h0 * h0 + h1 * h1;
    }
    hmax[(size_t)p0 * O + o] = hm0;
    hmax[(size_t)(p0 + 1) * O + o] = hm1;
    int slot = blockIdx.x & (SLOTS - 1);
    atomicAdd(&s1p[slot * O + o], ts1);
    atomicAdd(&s2p[slot * O + o], ts2);
}

// ---------------- dense split GEMM: bacc[BN][O] = hc[:, COFF:COFF+C] @ Wd^T (fp32 out)
// O split across blockIdx.y (64-wide tiles, NT=2) to keep VGPR low / occupancy high.
template <int O, int C, int COFF>
__launch_bounds__(256, 4)
__global__ void k_gemms(const unsigned short* __restrict__ hcH,
                        const unsigned short* __restrict__ hcL,
                        const unsigned short* __restrict__ WdH,
                        const unsigned short* __restrict__ WdL,
                        float* __restrict__ bacc) {
    constexpr int KS = C / 16;
    int tid = threadIdx.x, wave = tid >> 6, lane = tid & 63;
    int row = lane & 31, half = lane >> 5;
    int p0 = blockIdx.x * 128 + wave * 32;
    int ob = blockIdx.y * 64;
    const unsigned short* aH = hcH + (size_t)(p0 + row) * 512 + COFF;
    const unsigned short* aL = hcL + (size_t)(p0 + row) * 512 + COFF;
    f32x16 acc[2];
#pragma unroll
    for (int nt = 0; nt < 2; ++nt)
#pragma unroll
        for (int r = 0; r < 16; ++r) acc[nt][r] = 0.f;

#pragma unroll 2
    for (int ks = 0; ks < KS; ++ks) {
        int k0 = ks * 16 + half * 8;
        bf16x8 avh = *(const bf16x8*)(aH + k0);
        bf16x8 avl = *(const bf16x8*)(aL + k0);
#pragma unroll
        for (int nt = 0; nt < 2; ++nt) {
            int j = ob + nt * 32 + row;
            bf16x8 bvh = *(const bf16x8*)(WdH + (size_t)j * C + k0);
            bf16x8 bvl = *(const bf16x8*)(WdL + (size_t)j * C + k0);
            acc[nt] = __builtin_amdgcn_mfma_f32_32x32x16_bf16(avh, bvh, acc[nt], 0, 0, 0);
            acc[nt] = __builtin_amdgcn_mfma_f32_32x32x16_bf16(avh, bvl, acc[nt], 0, 0, 0);
            acc[nt] = __builtin_amdgcn_mfma_f32_32x32x16_bf16(avl, bvh, acc[nt], 0, 0, 0);
        }
    }
#pragma unroll
    for (int nt = 0; nt < 2; ++nt)
#pragma unroll
        for (int r = 0; r < 16; ++r) {
            int i = (r & 3) + 8 * (r >> 2) + 4 * half;
            bacc[(size_t)(p0 + i) * O + ob + nt * 32 + row] = acc[nt][r];
        }
}

// ---------------- MFMA split edge conv: per-wave per-point 32-row GEMM over K=C (nbr only)
// A rows 0-19 = neighbors, 20-31 pad (ignored). O split across blockIdx.y (NT=2).
template <int O, int C, int COFF>
__launch_bounds__(256, 4)
__global__ void k_convms(const unsigned short* __restrict__ hcH,
                         const unsigned short* __restrict__ hcL,
                         const int* __restrict__ gidx,
                         const unsigned short* __restrict__ WaH,
                         const unsigned short* __restrict__ WaL,
                         const float* __restrict__ bacc,
                         float* __restrict__ hmax, float* __restrict__ s1p,
                         float* __restrict__ s2p) {
    constexpr int KS = C / 16, PPW = 4;
    int tid = threadIdx.x, wave = tid >> 6, lane = tid & 63;
    int row = lane & 31, half = lane >> 5;
    int pbase = (blockIdx.x * 4 + wave) * PPW;
    int ob = blockIdx.y * 64;
    int b = pbase >> 11;

    float ts1[2], ts2[2];
#pragma unroll
    for (int nt = 0; nt < 2; ++nt) { ts1[nt] = 0.f; ts2[nt] = 0.f; }

#pragma unroll 1
    for (int pp = 0; pp < PPW; ++pp) {
        int p = pbase + pp;
        int nidx = gidx[(size_t)p * KK + (row < KK ? row : 0)];
        const unsigned short* aH = hcH + (size_t)(b * 2048 + nidx) * 512 + COFF;
        const unsigned short* aL = hcL + (size_t)(b * 2048 + nidx) * 512 + COFF;
        f32x16 acc[2];
#pragma unroll
        for (int nt = 0; nt < 2; ++nt)
#pragma unroll
            for (int r = 0; r < 16; ++r) acc[nt][r] = 0.f;

#pragma unroll 2
        for (int ks = 0; ks < KS; ++ks) {
            int k0 = ks * 16 + half * 8;
            bf16x8 avh = *(const bf16x8*)(aH + k0);
            bf16x8 avl = *(const bf16x8*)(aL + k0);
#pragma unroll
            for (int nt = 0; nt < 2; ++nt) {
                int j = ob + nt * 32 + row;
                bf16x8 bvh = *(const bf16x8*)(WaH + (size_t)j * C + k0);
                bf16x8 bvl = *(const bf16x8*)(WaL + (size_t)j * C + k0);
                acc[nt] = __builtin_amdgcn_mfma_f32_32x32x16_bf16(avh, bvh, acc[nt], 0, 0, 0);
                acc[nt] = __builtin_amdgcn_mfma_f32_32x32x16_bf16(avh, bvl, acc[nt], 0, 0, 0);
                acc[nt] = __builtin_amdgcn_mfma_f32_32x32x16_bf16(avl, bvh, acc[nt], 0, 0, 0);
            }
        }
        // epilogue: D row i = (r&3)+8*(r>>2)+4*half, col = ob + nt*32 + row
#pragma unroll
        for (int nt = 0; nt < 2; ++nt) {
            int col = ob + nt * 32 + row;
            float bf = bacc[(size_t)p * O + col];
            float mx = NEG;
#pragma unroll
            for (int r = 0; r < 16; ++r) {
                int i = (r & 3) + 8 * (r >> 2) + 4 * half;
                if (i < KK) {
                    float v = acc[nt][r] + bf;
                    mx = fmaxf(mx, v);
                    ts1[nt] += v; ts2[nt] += v * v;
                }
            }
            float mo = __shfl_xor(mx, 32);
            mx = fmaxf(mx, mo);
            if (half == 0) hmax[(size_t)p * O + col] = mx;
        }
    }
    int slot = blockIdx.x & (SLOTSM - 1);
#pragma unroll
    for (int nt = 0; nt < 2; ++nt) {
        float a1 = ts1[nt] + __shfl_xor(ts1[nt], 32);
        float a2 = ts2[nt] + __shfl_xor(ts2[nt], 32);
        if (half == 0) {
            atomicAdd(&s1p[slot * O + ob + nt * 32 + row], a1);
            atomicAdd(&s2p[slot * O + ob + nt * 32 + row], a2);
        }
    }
}

// ---------------- reduce slotted stats -> s1g/s2g
__global__ void k_redslots(const float* __restrict__ s1p, const float* __restrict__ s2p,
                           int O, int S, float* __restrict__ s1g, float* __restrict__ s2g) {
    int o = blockIdx.x * 256 + threadIdx.x;
    if (o >= O) return;
    float a = 0.f, c = 0.f;
    for (int s = 0; s < S; ++s) { a += s1p[s * O + o]; c += s2p[s * O + o]; }
    s1g[o] = a; s2g[o] = c;
}

// ---------------- BN(+leaky) on per-point max; writes split hi/lo bf16
__global__ void k_bnmax(const float* __restrict__ hmax, int O, const float* __restrict__ s1g,
                        const float* __restrict__ s2g, const float* __restrict__ gam,
                        const float* __restrict__ bet, unsigned short* __restrict__ outH,
                        unsigned short* __restrict__ outL, int ostride, int ooff,
                        float inv_cnt) {
    int i = blockIdx.x * 256 + threadIdx.x;
    if (i >= BN * O) return;
    int o = i % O, p = i / O;
    float m = s1g[o] * inv_cnt;
    float v = s2g[o] * inv_cnt - m * m;
    float rs = rsqrtf(v + EPSBN);
    float y = leaky(gam[o] * (hmax[i] - m) * rs + bet[o]);
    size_t oi = (size_t)p * ostride + ooff + o;
    split2(y, outH[oi], outL[oi]);
}

// ---------------- tiled transpose from hi/lo bf16: cols [coff+o0, ...) -> hcT [O][BN] fp32
__global__ void k_xposeB(const unsigned short* __restrict__ inH,
                         const unsigned short* __restrict__ inL, int coff,
                         float* __restrict__ out) {
    __shared__ float tile[64][65];
    int tx = threadIdx.x & 63, ty = threadIdx.x >> 6;
    int p0 = blockIdx.x * 64, o0 = blockIdx.y * 64;
    for (int i = ty; i < 64; i += 4) {
        size_t idx = (size_t)(p0 + i) * 512 + coff + o0 + tx;
        tile[i][tx] = b2f(inH[idx]) + b2f(inL[idx]);
    }
    __syncthreads();
    for (int i = ty; i < 64; i += 4)
        out[(size_t)(o0 + i) * BN + p0 + tx] = tile[tx][i];
}

// ---------------- w5 split GEMM: g5 = hc[BN][512] @ w5^T -> [BN][1024] + stats
// O split across blockIdx.y (256-wide block tiles; per wave 64 cols, NT=2).
__launch_bounds__(256, 4)
__global__ void k_w5ms(const unsigned short* __restrict__ hcH,
                       const unsigned short* __restrict__ hcL,
                       const unsigned short* __restrict__ w5H,
                       const unsigned short* __restrict__ w5L,
                       float* __restrict__ g5, float* __restrict__ s1p,
                       float* __restrict__ s2p) {
    int tid = threadIdx.x, wave = tid >> 6, lane = tid & 63;
    int row = lane & 31, half = lane >> 5;
    int p0 = blockIdx.x * 32;
    int ob = blockIdx.y * 256 + wave * 64;
    const unsigned short* aH = hcH + (size_t)(p0 + row) * 512;
    const unsigned short* aL = hcL + (size_t)(p0 + row) * 512;
    f32x16 acc[2];
#pragma unroll
    for (int nt = 0; nt < 2; ++nt)
#pragma unroll
        for (int r = 0; r < 16; ++r) acc[nt][r] = 0.f;

#pragma unroll 2
    for (int ks = 0; ks < 32; ++ks) {
        int k0 = ks * 16 + half * 8;
        bf16x8 avh = *(const bf16x8*)(aH + k0);
        bf16x8 avl = *(const bf16x8*)(aL + k0);
#pragma unroll
        for (int nt = 0; nt < 2; ++nt) {
            int j = ob + nt * 32 + row;
            bf16x8 bvh = *(const bf16x8*)(w5H + (size_t)j * 512 + k0);
            bf16x8 bvl = *(const bf16x8*)(w5L + (size_t)j * 512 + k0);
            acc[nt] = __builtin_amdgcn_mfma_f32_32x32x16_bf16(avh, bvh, acc[nt], 0, 0, 0);
            acc[nt] = __builtin_amdgcn_mfma_f32_32x32x16_bf16(avh, bvl, acc[nt], 0, 0, 0);
            acc[nt] = __builtin_amdgcn_mfma_f32_32x32x16_bf16(avl, bvh, acc[nt], 0, 0, 0);
        }
    }
    int slot = blockIdx.x & (SLOTSW - 1);
#pragma unroll
    for (int nt = 0; nt < 2; ++nt) {
        int j = ob + nt * 32 + row;
        float s1 = 0.f, s2 = 0.f;
#pragma unroll
        for (int r = 0; r < 16; ++r) {
            int i = (r & 3) + 8 * (r >> 2) + 4 * half;
            float v = acc[nt][r];
            g5[(size_t)(p0 + i) * 1024 + j] = v;
            s1 += v; s2 += v * v;
        }
        s1 += __shfl_xor(s1, 32);
        s2 += __shfl_xor(s2, 32);
        if (half == 0) {
            atomicAdd(&s1p[slot * 1024 + j], s1);
            atomicAdd(&s2p[slot * 1024 + j], s2);
        }
    }
}

// ---------------- pool: per (b, o-tile, n-chunk) partial max / partial sum
__global__ void k_pool(const float* __restrict__ gbuf, const float* __restrict__ s1g,
                       const float* __restrict__ s2g, const float* __restrict__ gam,
                       const float* __restrict__ bet, float* __restrict__ pmax,
                       float* __restrict__ psum) {
    int t = threadIdx.x;
    int blk = blockIdx.x;
    int nc = blk & 7, ot = (blk >> 3) & 3, b = blk >> 5;
    int o = ot * 256 + t;
    float m = s1g[o] * (1.f / 16384.f);
    float v = s2g[o] * (1.f / 16384.f) - m * m;
    float rs = rsqrtf(v + EPSBN);
    float ga = gam[o], be = bet[o];
    float vmax = NEG, vsum = 0.f;
    for (int j = 0; j < 256; ++j) {
        int n = nc * 256 + j;
        float x = gbuf[((size_t)b * NP + n) * 1024 + o];
        float y = leaky(ga * (x - m) * rs + be);
        vmax = fmaxf(vmax, y);
        vsum += y;
    }
    pmax[(b * 1024 + o) * 8 + nc] = vmax;
    psum[(b * 1024 + o) * 8 + nc] = vsum;
}

__global__ void k_poolfin(const float* __restrict__ pmax, const float* __restrict__ psum,
                          float* __restrict__ pooled) {
    int i = blockIdx.x * 256 + threadIdx.x;
    if (i >= 8192) return;
    float mx = NEG, sm = 0.f;
    for (int j = 0; j < 8; ++j) {
        mx = fmaxf(mx, pmax[i * 8 + j]);
        sm += psum[i * 8 + j];
    }
    int b = i >> 10, o = i & 1023;
    pooled[b * 2048 + o] = mx;
    pooled[b * 2048 + 1024 + o] = sm * (1.f / 2048.f);
}

// ---------------- small FC: z[b][o] = in[b] . W[o] (+bias)
template <int CIN>
__global__ void k_fc(const float* __restrict__ in, const float* __restrict__ W,
                     const float* __restrict__ bias, int O, float* __restrict__ z) {
    int i = blockIdx.x * 256 + threadIdx.x;
    if (i >= NB * O) return;
    int b = i / O, o = i % O;
    const float* wr = W + (size_t)o * CIN;
    const float* ir = in + (size_t)b * CIN;
    float acc = 0.f;
#pragma unroll 4
    for (int cq = 0; cq < CIN / 4; ++cq) {
        float4 wv = *(const float4*)&wr[cq * 4];
        float4 iv = *(const float4*)&ir[cq * 4];
        acc += wv.x * iv.x + wv.y * iv.y + wv.z * iv.z + wv.w * iv.w;
    }
    z[i] = acc + (bias ? bias[o] : 0.f);
}

// ---------------- BN over batch (8 samples) + leaky
__global__ void k_bnb(const float* __restrict__ z, int O, const float* __restrict__ gam,
                      const float* __restrict__ bet, float* __restrict__ out, int ostride,
                      int ooff) {
    int o = blockIdx.x * 256 + threadIdx.x;
    if (o >= O) return;
    float s1 = 0.f, s2 = 0.f;
#pragma unroll
    for (int b = 0; b < NB; ++b) {
        float x = z[b * O + o];
        s1 += x; s2 += x * x;
    }
    float m = s1 * 0.125f, v = s2 * 0.125f - m * m;
    float rs = rsqrtf(v + EPSBN);
    float ga = gam[o], be = bet[o];
    for (int b = 0; b < NB; ++b) {
        float y = ga * (z[b * O + o] - m) * rs + be;
        out[b * ostride + ooff + o] = leaky(y);
    }
}

// ---------------- head
__global__ void k_head(const float* __restrict__ hf, const float* __restrict__ wh,
                       const float* __restrict__ bh, const float* __restrict__ g8,
                       const float* __restrict__ b8, float* __restrict__ out) {
    __shared__ float zh[56];
    int t = threadIdx.x;
    if (t < 56) {
        int b = t / 7, o = t % 7;
        float acc = bh[o];
        for (int c = 0; c < 768; ++c) acc += hf[b * 768 + c] * wh[o * 768 + c];
        zh[t] = acc;
    }
    __syncthreads();
    if (t < 7) {
        float s1 = 0.f, s2 = 0.f;
        for (int b = 0; b < NB; ++b) {
            float x = zh[b * 7 + t];
            s1 += x; s2 += x * x;
        }
        float m = s1 * 0.125f, v = s2 * 0.125f - m * m;
        float rs = rsqrtf(v + EPSBN);
        for (int b = 0; b < NB; ++b) {
            float y = g8[t] * (zh[b * 7 + t] - m) * rs + b8[t];
            out[b * 7 + t] = fmaxf(y, 0.f);
        }
    }
}

extern "C" void kernel_launch(void* const* d_in, const int* in_sizes, int n_in, void* d_out,
                              int out_size, void* d_ws, size_t ws_size, hipStream_t stream) {
    const float* x[3] = {(const float*)d_in[0], (const float*)d_in[1], (const float*)d_in[2]};
    const float* w1 = (const float*)d_in[3];
    const float* w2 = (const float*)d_in[4];
    const float* w3 = (const float*)d_in[5];
    const float* w4 = (const float*)d_in[6];
    const float* w5 = (const float*)d_in[7];
    const float* wl1 = (const float*)d_in[8];
    const float* wl2 = (const float*)d_in[9];
    const float* bl2 = (const float*)d_in[10];
    const float* whead = (const float*)d_in[11];
    const float* bhead = (const float*)d_in[12];
    const float *g1 = (const float*)d_in[13], *b1 = (const float*)d_in[14];
    const float *g2 = (const float*)d_in[15], *b2 = (const float*)d_in[16];
    const float *g3 = (const float*)d_in[17], *b3 = (const float*)d_in[18];
    const float *g4 = (const float*)d_in[19], *b4 = (const float*)d_in[20];
    const float *g5 = (const float*)d_in[21], *b5 = (const float*)d_in[22];
    const float *g6 = (const float*)d_in[23], *b6 = (const float*)d_in[24];
    const float *g7 = (const float*)d_in[25], *b7 = (const float*)d_in[26];
    const float *g8 = (const float*)d_in[27], *b8 = (const float*)d_in[28];

    char* w = (char*)d_ws;
    auto alloc = [&](size_t bytes) {
        char* p = w;
        w += (bytes + 255) & ~(size_t)255;
        return p;
    };
    float* xt   = (float*)alloc((size_t)BN * 4 * 4);
    float* xtT  = (float*)alloc((size_t)4 * BN * 4);
    unsigned short* hcH = (unsigned short*)alloc((size_t)BN * 512 * 2);
    unsigned short* hcL = (unsigned short*)alloc((size_t)BN * 512 * 2);
    float* hcT  = (float*)alloc((size_t)128 * BN * 4);
    float* gbig = (float*)alloc((size_t)BN * 1024 * 4);  // hmax[0,BN*256) | bacc@BN*512 | g5 full
    int*   idx  = (int*)alloc((size_t)BN * KK * 4);
    float* sqv  = (float*)alloc((size_t)BN * 4);
    float* s1g  = (float*)alloc(1024 * 4);
    float* s2g  = (float*)alloc(1024 * 4);
    float* spart  = (float*)alloc(2 * SLOTS * 256 * 4);     // conv1 fp32 stats
    float* spartC = (float*)alloc(2 * SLOTSM * 256 * 4);    // mfma conv stats
    float* spartW = (float*)alloc(2 * SLOTSW * 1024 * 4);   // w5 stats
    float* pmax = (float*)alloc(8 * 1024 * 8 * 4);
    float* psum = (float*)alloc(8 * 1024 * 8 * 4);
    float* pooled = (float*)alloc(8 * 2048 * 4);
    float* z1 = (float*)alloc(8 * 512 * 4);
    float* a1 = (float*)alloc(8 * 512 * 4);
    float* z2 = (float*)alloc(8 * 256 * 4);
    float* hfeat = (float*)alloc(8 * 768 * 4);
    float* Wa1 = (float*)alloc(4 * 64 * 4);
    float* Wd1 = (float*)alloc(4 * 64 * 4);
    unsigned short* WaH2 = (unsigned short*)alloc(64 * 64 * 2);
    unsigned short* WaL2 = (unsigned short*)alloc(64 * 64 * 2);
    unsigned short* WdH2 = (unsigned short*)alloc(64 * 64 * 2);
    unsigned short* WdL2 = (unsigned short*)alloc(64 * 64 * 2);
    unsigned short* WaH3 = (unsigned short*)alloc(128 * 64 * 2);
    unsigned short* WaL3 = (unsigned short*)alloc(128 * 64 * 2);
    unsigned short* WdH3 = (unsigned short*)alloc(128 * 64 * 2);
    unsigned short* WdL3 = (unsigned short*)alloc(128 * 64 * 2);
    unsigned short* WaH4 = (unsigned short*)alloc(256 * 128 * 2);
    unsigned short* WaL4 = (unsigned short*)alloc(256 * 128 * 2);
    unsigned short* WdH4 = (unsigned short*)alloc(256 * 128 * 2);
    unsigned short* WdL4 = (unsigned short*)alloc(256 * 128 * 2);
    unsigned short* w5H  = (unsigned short*)alloc(1024 * 512 * 2);
    unsigned short* w5L  = (unsigned short*)alloc(1024 * 512 * 2);
    float* s1p = spart;
    float* s2p = spart + SLOTS * 256;
    float* s1pc = spartC;
    float* s2pc = spartC + SLOTSM * 256;
    float* s1pw = spartW;
    float* s2pw = spartW + SLOTSW * 1024;
    float* baccP = gbig + (size_t)BN * 512;   // aliased: disjoint from hmax region

    // weight prep (plane-independent)
    k_prepw<<<(4 * 64 + 255) / 256, 256, 0, stream>>>(w1, 64, 3, 4, Wa1, Wd1);
    k_prepws<<<(64 * 64 + 255) / 256, 256, 0, stream>>>(w2, 64, 64, WaH2, WaL2, WdH2, WdL2);
    k_prepws<<<(128 * 64 + 255) / 256, 256, 0, stream>>>(w3, 128, 64, WaH3, WaL3, WdH3, WdL3);
    k_prepws<<<(256 * 128 + 255) / 256, 256, 0, stream>>>(w4, 256, 128, WaH4, WaL4, WdH4, WdL4);
    k_splitw5<<<(1024 * 512) / 256, 256, 0, stream>>>(w5, w5H, w5L);

    const float inv_e = 1.f / (float)(BN * KK);
    for (int p = 0; p < 3; ++p) {
        k_transpose<<<BN / 256, 256, 0, stream>>>(x[p], xt, xtT);

        // ---- layer 1 (fp32): C=3 pad 4, O=64 -> cols 0:64
        k_sq<4><<<BN / 256, 256, 0, stream>>>(xtT, sqv);
        k_knn<4><<<NB * (NP / 8), 256, 0, stream>>>(xtT, sqv, idx);
        hipMemsetAsync(spart, 0, 2 * SLOTS * 256 * 4, stream);
        k_conv<64, 4><<<BN / 2, 64, 0, stream>>>(xt, 4, idx, Wa1, Wd1, gbig, s1p, s2p);
        k_redslots<<<1, 256, 0, stream>>>(s1p, s2p, 64, SLOTS, s1g, s2g);
        k_bnmax<<<(BN * 64) / 256, 256, 0, stream>>>(gbig, 64, s1g, s2g, g1, b1, hcH, hcL, 512, 0, inv_e);
        k_xposeB<<<dim3(BN / 64, 1), 256, 0, stream>>>(hcH, hcL, 0, hcT);

        // ---- layer 2 (mfma split): C=64 @ cols 0:64, O=64 -> cols 64:128
        k_sq<64><<<BN / 256, 256, 0, stream>>>(hcT, sqv);
        k_knn<64><<<NB * (NP / 8), 256, 0, stream>>>(hcT, sqv, idx);
        k_gemms<64, 64, 0><<<dim3(BN / 128, 1), 256, 0, stream>>>(hcH, hcL, WdH2, WdL2, baccP);
        hipMemsetAsync(spartC, 0, 2 * SLOTSM * 256 * 4, stream);
        k_convms<64, 64, 0><<<dim3(BN / 16, 1), 256, 0, stream>>>(hcH, hcL, idx, WaH2, WaL2, baccP, gbig, s1pc, s2pc);
        k_redslots<<<1, 256, 0, stream>>>(s1pc, s2pc, 64, SLOTSM, s1g, s2g);
        k_bnmax<<<(BN * 64) / 256, 256, 0, stream>>>(gbig, 64, s1g, s2g, g2, b2, hcH, hcL, 512, 64, inv_e);
        k_xposeB<<<dim3(BN / 64, 1), 256, 0, stream>>>(hcH, hcL, 64, hcT);

        // ---- layer 3 (mfma split): C=64 @ cols 64:128, O=128 -> cols 128:256
        k_sq<64><<<BN / 256, 256, 0, stream>>>(hcT, sqv);
        k_knn<64><<<NB * (NP / 8), 256, 0, stream>>>(hcT, sqv, idx);
        k_gemms<128, 64, 64><<<dim3(BN / 128, 2), 256, 0, stream>>>(hcH, hcL, WdH3, WdL3, baccP);
        hipMemsetAsync(spartC, 0, 2 * SLOTSM * 256 * 4, stream);
        k_convms<128, 64, 64><<<dim3(BN / 16, 2), 256, 0, stream>>>(hcH, hcL, idx, WaH3, WaL3, baccP, gbig, s1pc, s2pc);
        k_redslots<<<1, 256, 0, stream>>>(s1pc, s2pc, 128, SLOTSM, s1g, s2g);
        k_bnmax<<<(BN * 128) / 256, 256, 0, stream>>>(gbig, 128, s1g, s2g, g3, b3, hcH, hcL, 512, 128, inv_e);
        k_xposeB<<<dim3(BN / 64, 2), 256, 0, stream>>>(hcH, hcL, 128, hcT);

        // ---- layer 4 (mfma split): C=128 @ cols 128:256, O=256 -> cols 256:512
        k_sq<128><<<BN / 256, 256, 0, stream>>>(hcT, sqv);
        k_knn<128><<<NB * (NP / 8), 256, 0, stream>>>(hcT, sqv, idx);
        k_gemms<256, 128, 128><<<dim3(BN / 128, 4), 256, 0, stream>>>(hcH, hcL, WdH4, WdL4, baccP);
        hipMemsetAsync(spartC, 0, 2 * SLOTSM * 256 * 4, stream);
        k_convms<256, 128, 128><<<dim3(BN / 16, 4), 256, 0, stream>>>(hcH, hcL, idx, WaH4, WaL4, baccP, gbig, s1pc, s2pc);
        k_redslots<<<1, 256, 0, stream>>>(s1pc, s2pc, 256, SLOTSM, s1g, s2g);
        k_bnmax<<<(BN * 256) / 256, 256, 0, stream>>>(gbig, 256, s1g, s2g, g4, b4, hcH, hcL, 512, 256, inv_e);

        // ---- w5 (mfma split) + BN + pool
        hipMemsetAsync(spartW, 0, 2 * SLOTSW * 1024 * 4, stream);
        k_w5ms<<<dim3(BN / 32, 4), 256, 0, stream>>>(hcH, hcL, w5H, w5L, gbig, s1pw, s2pw);
        k_redslots<<<4, 256, 0, stream>>>(s1pw, s2pw, 1024, SLOTSW, s1g, s2g);
        k_pool<<<256, 256, 0, stream>>>(gbig, s1g, s2g, g5, b5, pmax, psum);
        k_poolfin<<<32, 256, 0, stream>>>(pmax, psum, pooled);

        // ---- FC head of the plane
        k_fc<2048><<<(8 * 512 + 255) / 256, 256, 0, stream>>>(pooled, wl1, nullptr, 512, z1);
        k_bnb<<<2, 256, 0, stream>>>(z1, 512, g6, b6, a1, 512, 0);
        k_fc<512><<<(8 * 256 + 255) / 256, 256, 0, stream>>>(a1, wl2, bl2, 256, z2);
        k_bnb<<<1, 256, 0, stream>>>(z2, 256, g7, b7, hfeat, 768, p * 256);
    }
    k_head<<<1, 64, 0, stream>>>(hfeat, whead, bhead, g8, b8, (float*)d_out);
}

// Round 9
// 4324.327 us; speedup vs baseline: 2.0517x; 1.2351x over previous
//
#include <hip/hip_runtime.h>
#include <hip/hip_bf16.h>
#include <cstdint>
#include <cstddef>

constexpr int NB = 8;      // batch
constexpr int NP = 2048;   // points per cloud
constexpr int BN = NB * NP;  // 16384
constexpr int KK = 20;     // neighbors
constexpr float EPSBN = 1e-5f;
constexpr float NEG = -3.402823466e38f;
constexpr int SLOTS = 8;    // fp32 conv1 stats slots
constexpr int SLOTSM = 32;  // gmax stats slots
constexpr int SLOTSW = 8;   // w5 stats slots

typedef __attribute__((ext_vector_type(8))) short bf16x8;   // 8 bf16 = 4 VGPRs
typedef __attribute__((ext_vector_type(16))) float f32x16;  // 32x32 MFMA acc

__device__ __forceinline__ float leaky(float x) { return x > 0.f ? x : 0.2f * x; }

__device__ __forceinline__ void split2(float x, unsigned short& h, unsigned short& l) {
    __hip_bfloat16 hh = __float2bfloat16(x);
    float hf = __bfloat162float(hh);
    __hip_bfloat16 ll = __float2bfloat16(x - hf);
    h = *reinterpret_cast<unsigned short*>(&hh);
    l = *reinterpret_cast<unsigned short*>(&ll);
}

__device__ __forceinline__ float b2f(unsigned short u) {
    __hip_bfloat16 h = *reinterpret_cast<__hip_bfloat16*>(&u);
    return __bfloat162float(h);
}

// float -> orderable u32 (ascending uint == ascending float)
__device__ __forceinline__ unsigned int f2key(float f) {
    unsigned int u = __float_as_uint(f);
    return u ^ (unsigned int)(((int)u >> 31) | 0x80000000);
}

// ---------------- transpose x [8,3,2048] -> xt [BN][4] (pad c3=0) and xtT [4][BN]
__global__ void k_transpose(const float* __restrict__ x, float* __restrict__ xt,
                            float* __restrict__ xtT) {
    int i = blockIdx.x * 256 + threadIdx.x;
    if (i >= BN) return;
    int b = i >> 11, n = i & 2047;
    float v0 = x[(b * 3 + 0) * NP + n];
    float v1 = x[(b * 3 + 1) * NP + n];
    float v2 = x[(b * 3 + 2) * NP + n];
    float4 v; v.x = v0; v.y = v1; v.z = v2; v.w = 0.f;
    *(float4*)&xt[(size_t)i * 4] = v;
    xtT[0 * BN + i] = v0;
    xtT[1 * BN + i] = v1;
    xtT[2 * BN + i] = v2;
    xtT[3 * BN + i] = 0.f;
}

// ---------------- sq[i] = |F_i|^2 from transposed features FT [CP][BN]
template <int CP>
__global__ void k_sq(const float* __restrict__ FT, float* __restrict__ sq) {
    int i = blockIdx.x * 256 + threadIdx.x;
    if (i >= BN) return;
    float s = 0.f;
#pragma unroll
    for (int c = 0; c < CP; ++c) {
        float f = FT[(size_t)c * BN + i];
        s += f * f;
    }
    sq[i] = s;
}

// ---------------- knn: top-20 farthest, fp32 distances, radix-descend selection
template <int CP>
__launch_bounds__(256, 2)
__global__ void k_knn(const float* __restrict__ FT, const float* __restrict__ sq,
                      int* __restrict__ gidx) {
    constexpr int R = 8;
    __shared__ unsigned int ds[R][NP];   // 64 KiB of keys
    int t = threadIdx.x;
    int b = blockIdx.x >> 8;
    int n0 = (blockIdx.x & 255) * R;
    const float* FTb = FT + (size_t)b * NP;
    const float* sqb = sq + (size_t)b * NP;

    float acc[R][8];
#pragma unroll
    for (int r = 0; r < R; ++r)
#pragma unroll
        for (int mi = 0; mi < 8; ++mi) acc[r][mi] = 0.f;

    for (int cq = 0; cq < CP / 4; ++cq) {
        float4 c4[R];
#pragma unroll
        for (int r = 0; r < R; ++r) {
            c4[r].x = FTb[(size_t)(cq * 4 + 0) * BN + n0 + r];
            c4[r].y = FTb[(size_t)(cq * 4 + 1) * BN + n0 + r];
            c4[r].z = FTb[(size_t)(cq * 4 + 2) * BN + n0 + r];
            c4[r].w = FTb[(size_t)(cq * 4 + 3) * BN + n0 + r];
        }
#pragma unroll
        for (int mi = 0; mi < 8; ++mi) {
            int m = t + mi * 256;
            float f0 = FTb[(size_t)(cq * 4 + 0) * BN + m];
            float f1 = FTb[(size_t)(cq * 4 + 1) * BN + m];
            float f2 = FTb[(size_t)(cq * 4 + 2) * BN + m];
            float f3 = FTb[(size_t)(cq * 4 + 3) * BN + m];
#pragma unroll
            for (int r = 0; r < R; ++r)
                acc[r][mi] += f0 * c4[r].x + f1 * c4[r].y + f2 * c4[r].z + f3 * c4[r].w;
        }
    }
#pragma unroll
    for (int mi = 0; mi < 8; ++mi) {
        int m = t + mi * 256;
        float sm = sqb[m];
#pragma unroll
        for (int r = 0; r < R; ++r) ds[r][m] = f2key(sm - 2.f * acc[r][mi]);
    }
    __syncthreads();

    int wave = t >> 6, lane = t & 63;
    unsigned long long below = (1ull << lane) - 1ull;
#pragma unroll 1
    for (int rr = 0; rr < 2; ++rr) {
        int r = wave * 2 + rr;
        unsigned int kv[32];
#pragma unroll
        for (int j = 0; j < 32; ++j) kv[j] = ds[r][lane + 64 * j];

        unsigned int T = 0;
#pragma unroll 1
        for (int bit = 31; bit >= 0; --bit) {
            unsigned int tt = T | (1u << bit);
            int c = 0;
#pragma unroll
            for (int j = 0; j < 32; ++j)
                c += (int)__popcll(__ballot(kv[j] >= tt));
            if (c >= KK) T = tt;
        }

        int obase = (b * NP + n0 + r) * KK;
        int base = 0;
#pragma unroll 1
        for (int j = 0; j < 32; ++j) {
            bool pg = kv[j] > T;
            unsigned long long mk = __ballot(pg);
            if (pg) gidx[obase + base + (int)__popcll(mk & below)] = lane + 64 * j;
            base += (int)__popcll(mk);
        }
        int rem = KK - base;
#pragma unroll 1
        for (int j = 0; j < 32; ++j) {
            if (rem <= 0) break;
            bool pe = kv[j] == T;
            unsigned long long mk = __ballot(pe);
            int myp = (int)__popcll(mk & below);
            if (pe && myp < rem) gidx[obase + base + myp] = lane + 64 * j;
            int cnt = (int)__popcll(mk);
            int take = cnt < rem ? cnt : rem;
            base += take; rem -= take;
        }
    }
}

// ---------------- prep (conv1, fp32): W [O][2C] -> WaT [CP][O], WdT [CP][O]
__global__ void k_prepw(const float* __restrict__ W, int O, int Cact, int CP,
                        float* __restrict__ WaT, float* __restrict__ WdT) {
    int i = blockIdx.x * 256 + threadIdx.x;
    if (i >= CP * O) return;
    int c = i / O, o = i % O;
    float wa = (c < Cact) ? W[o * 2 * Cact + c] : 0.f;
    float wb = (c < Cact) ? W[o * 2 * Cact + Cact + c] : 0.f;
    WaT[i] = wa;
    WdT[i] = wb - wa;
}

// ---------------- prep combined: W [O][2C] fp32 -> Wcmb [2O][C] split h/l
// rows r<O: Wa row r ; rows r>=O: Wd=Wb-Wa row (r-O)
__global__ void k_prepws2(const float* __restrict__ W, int O, int C,
                          unsigned short* __restrict__ WcH, unsigned short* __restrict__ WcL) {
    int i = blockIdx.x * 256 + threadIdx.x;
    if (i >= 2 * O * C) return;
    int r = i / C, k = i % C;
    float v;
    if (r < O) v = W[r * 2 * C + k];
    else {
        int o = r - O;
        v = W[o * 2 * C + C + k] - W[o * 2 * C + k];
    }
    split2(v, WcH[i], WcL[i]);
}

// ---------------- split w5 [1024][512] fp32 -> hi/lo bf16
__global__ void k_splitw5(const float* __restrict__ w5, unsigned short* __restrict__ w5H,
                          unsigned short* __restrict__ w5L) {
    int i = blockIdx.x * 256 + threadIdx.x;
    if (i >= 1024 * 512) return;
    split2(w5[i], w5H[i], w5L[i]);
}

// ---------------- fp32 edge conv (layer 1 only, tiny C)
template <int O, int CP>
__launch_bounds__(O)
__global__ void k_conv(const float* __restrict__ F, int ld, const int* __restrict__ gidx,
                       const float* __restrict__ WaT, const float* __restrict__ WdT,
                       float* __restrict__ hmax, float* __restrict__ s1p,
                       float* __restrict__ s2p) {
    constexpr int CP4 = CP / 4;
    __shared__ float nbrT[2][CP][32];
    __shared__ float sctr[2][CP];
    __shared__ int sidx[2][KK];
    int t = threadIdx.x;
    int p0 = blockIdx.x * 2;
    int b = p0 >> 11;
    const float* Fb = F + (size_t)b * NP * ld;

    if (t < 2 * KK) {
        int pt = t / KK, k = t % KK;
        sidx[pt][k] = gidx[(size_t)(p0 + pt) * KK + k];
    }
    for (int e = t; e < 2 * CP; e += O) {
        int pt = e / CP, cc = e % CP;
        int n = (p0 + pt) & 2047;
        sctr[pt][cc] = Fb[(size_t)n * ld + cc];
    }
    __syncthreads();
    for (int e = t; e < 2 * KK * CP4; e += O) {
        int pt = e / (KK * CP4);
        int e2 = e % (KK * CP4);
        int k = e2 / CP4, cq = e2 % CP4;
        float4 f = *(const float4*)&Fb[(size_t)sidx[pt][k] * ld + cq * 4];
        int kp = (k + 4 * (cq & 7)) & 31;
        nbrT[pt][cq * 4 + 0][kp] = f.x;
        nbrT[pt][cq * 4 + 1][kp] = f.y;
        nbrT[pt][cq * 4 + 2][kp] = f.z;
        nbrT[pt][cq * 4 + 3][kp] = f.w;
    }
    __syncthreads();

    int o = t;
    float bacc0 = 0.f, bacc1 = 0.f;
#pragma unroll 4
    for (int c = 0; c < CP; ++c) {
        float w = WdT[c * O + o];
        bacc0 += sctr[0][c] * w;
        bacc1 += sctr[1][c] * w;
    }
    float a0[KK], a1[KK];
#pragma unroll
    for (int k = 0; k < KK; ++k) { a0[k] = 0.f; a1[k] = 0.f; }
#pragma unroll 2
    for (int c = 0; c < CP; ++c) {
        float w = WaT[c * O + o];
        int s = 4 * ((c >> 2) & 7);
#pragma unroll
        for (int kq = 0; kq < KK / 4; ++kq) {
            int kp = (4 * kq + s) & 31;
            float4 f0 = *(const float4*)&nbrT[0][c][kp];
            float4 f1 = *(const float4*)&nbrT[1][c][kp];
            a0[kq * 4 + 0] += w * f0.x; a1[kq * 4 + 0] += w * f1.x;
            a0[kq * 4 + 1] += w * f0.y; a1[kq * 4 + 1] += w * f1.y;
            a0[kq * 4 + 2] += w * f0.z; a1[kq * 4 + 2] += w * f1.z;
            a0[kq * 4 + 3] += w * f0.w; a1[kq * 4 + 3] += w * f1.w;
        }
    }
    float hm0 = NEG, hm1 = NEG, ts1 = 0.f, ts2 = 0.f;
#pragma unroll
    for (int k = 0; k < KK; ++k) {
        float h0 = a0[k] + bacc0;
        float h1 = a1[k] + bacc1;
        hm0 = fmaxf(hm0, h0); hm1 = fmaxf(hm1, h1);
        ts1 += h0 + h1; ts2 += h0 * h0 + h1 * h1;
    }
    hmax[(size_t)p0 * O + o] = hm0;
    hmax[(size_t)(p0 + 1) * O + o] = hm1;
    int slot = blockIdx.x & (SLOTS - 1);
    atomicAdd(&s1p[slot * O + o], ts1);
    atomicAdd(&s2p[slot * O + o], ts2);
}

// ---------------- dense split GEMM: Gz[BN][O] = hc[:, COFF:COFF+C] @ Wcmb^T (fp32 out)
// O split across blockIdx.y (64-wide tiles, NT=2). Regular, coalesced.
template <int O, int C, int COFF>
__launch_bounds__(256, 4)
__global__ void k_gemms(const unsigned short* __restrict__ hcH,
                        const unsigned short* __restrict__ hcL,
                        const unsigned short* __restrict__ WdH,
                        const unsigned short* __restrict__ WdL,
                        float* __restrict__ bacc) {
    constexpr int KS = C / 16;
    int tid = threadIdx.x, wave = tid >> 6, lane = tid & 63;
    int row = lane & 31, half = lane >> 5;
    int p0 = blockIdx.x * 128 + wave * 32;
    int ob = blockIdx.y * 64;
    const unsigned short* aH = hcH + (size_t)(p0 + row) * 512 + COFF;
    const unsigned short* aL = hcL + (size_t)(p0 + row) * 512 + COFF;
    f32x16 acc[2];
#pragma unroll
    for (int nt = 0; nt < 2; ++nt)
#pragma unroll
        for (int r = 0; r < 16; ++r) acc[nt][r] = 0.f;

#pragma unroll 2
    for (int ks = 0; ks < KS; ++ks) {
        int k0 = ks * 16 + half * 8;
        bf16x8 avh = *(const bf16x8*)(aH + k0);
        bf16x8 avl = *(const bf16x8*)(aL + k0);
#pragma unroll
        for (int nt = 0; nt < 2; ++nt) {
            int j = ob + nt * 32 + row;
            bf16x8 bvh = *(const bf16x8*)(WdH + (size_t)j * C + k0);
            bf16x8 bvl = *(const bf16x8*)(WdL + (size_t)j * C + k0);
            acc[nt] = __builtin_amdgcn_mfma_f32_32x32x16_bf16(avh, bvh, acc[nt], 0, 0, 0);
            acc[nt] = __builtin_amdgcn_mfma_f32_32x32x16_bf16(avh, bvl, acc[nt], 0, 0, 0);
            acc[nt] = __builtin_amdgcn_mfma_f32_32x32x16_bf16(avl, bvh, acc[nt], 0, 0, 0);
        }
    }
#pragma unroll
    for (int nt = 0; nt < 2; ++nt)
#pragma unroll
        for (int r = 0; r < 16; ++r) {
            int i = (r & 3) + 8 * (r >> 2) + 4 * half;
            bacc[(size_t)(p0 + i) * O + ob + nt * 32 + row] = acc[nt][r];
        }
}

// ---------------- gather-max epilogue: hmax[p,o] = max_k Gz[nbr_k, o] + bacc;
// Gz [BN][2O]: cols [0,O)=G (neighbor part), [O,2O)=bacc (center part). + BN stats.
template <int O>
__launch_bounds__(256)
__global__ void k_gmax(const float* __restrict__ Gz, const int* __restrict__ gidx,
                       float* __restrict__ hmax, float* __restrict__ s1p,
                       float* __restrict__ s2p) {
    constexpr int PB = 256 / O;      // points per block
    constexpr int O2 = 2 * O;
    __shared__ int sidx[PB][KK];
    int t = threadIdx.x;
    int pt = t / O, o = t % O;
    int p0 = blockIdx.x * PB;
    if (t < PB * KK) sidx[t / KK][t % KK] = gidx[(size_t)(p0 + t / KK) * KK + t % KK];
    __syncthreads();

    int p = p0 + pt;
    int b = p >> 11;
    const float* Gb = Gz + (size_t)b * 2048 * O2;
    float bacc = Gz[(size_t)p * O2 + O + o];
    float mx = NEG, ts1 = 0.f, ts2 = 0.f;
#pragma unroll 5
    for (int k = 0; k < KK; ++k) {
        float g = Gb[(size_t)sidx[pt][k] * O2 + o];
        float h = g + bacc;
        mx = fmaxf(mx, g);
        ts1 += h; ts2 += h * h;
    }
    hmax[(size_t)p * O + o] = mx + bacc;
    int slot = blockIdx.x & (SLOTSM - 1);
    atomicAdd(&s1p[slot * O + o], ts1);
    atomicAdd(&s2p[slot * O + o], ts2);
}

// ---------------- reduce slotted stats -> s1g/s2g
__global__ void k_redslots(const float* __restrict__ s1p, const float* __restrict__ s2p,
                           int O, int S, float* __restrict__ s1g, float* __restrict__ s2g) {
    int o = blockIdx.x * 256 + threadIdx.x;
    if (o >= O) return;
    float a = 0.f, c = 0.f;
    for (int s = 0; s < S; ++s) { a += s1p[s * O + o]; c += s2p[s * O + o]; }
    s1g[o] = a; s2g[o] = c;
}

// ---------------- BN(+leaky) on per-point max; writes split hi/lo bf16
__global__ void k_bnmax(const float* __restrict__ hmax, int O, const float* __restrict__ s1g,
                        const float* __restrict__ s2g, const float* __restrict__ gam,
                        const float* __restrict__ bet, unsigned short* __restrict__ outH,
                        unsigned short* __restrict__ outL, int ostride, int ooff,
                        float inv_cnt) {
    int i = blockIdx.x * 256 + threadIdx.x;
    if (i >= BN * O) return;
    int o = i % O, p = i / O;
    float m = s1g[o] * inv_cnt;
    float v = s2g[o] * inv_cnt - m * m;
    float rs = rsqrtf(v + EPSBN);
    float y = leaky(gam[o] * (hmax[i] - m) * rs + bet[o]);
    size_t oi = (size_t)p * ostride + ooff + o;
    split2(y, outH[oi], outL[oi]);
}

// ---------------- tiled transpose from hi/lo bf16: cols [coff+o0, ...) -> hcT [O][BN] fp32
__global__ void k_xposeB(const unsigned short* __restrict__ inH,
                         const unsigned short* __restrict__ inL, int coff,
                         float* __restrict__ out) {
    __shared__ float tile[64][65];
    int tx = threadIdx.x & 63, ty = threadIdx.x >> 6;
    int p0 = blockIdx.x * 64, o0 = blockIdx.y * 64;
    for (int i = ty; i < 64; i += 4) {
        size_t idx = (size_t)(p0 + i) * 512 + coff + o0 + tx;
        tile[i][tx] = b2f(inH[idx]) + b2f(inL[idx]);
    }
    __syncthreads();
    for (int i = ty; i < 64; i += 4)
        out[(size_t)(o0 + i) * BN + p0 + tx] = tile[tx][i];
}

// ---------------- w5 split GEMM: g5 = hc[BN][512] @ w5^T -> [BN][1024] + stats
__launch_bounds__(256, 4)
__global__ void k_w5ms(const unsigned short* __restrict__ hcH,
                       const unsigned short* __restrict__ hcL,
                       const unsigned short* __restrict__ w5H,
                       const unsigned short* __restrict__ w5L,
                       float* __restrict__ g5, float* __restrict__ s1p,
                       float* __restrict__ s2p) {
    int tid = threadIdx.x, wave = tid >> 6, lane = tid & 63;
    int row = lane & 31, half = lane >> 5;
    int p0 = blockIdx.x * 32;
    int ob = blockIdx.y * 256 + wave * 64;
    const unsigned short* aH = hcH + (size_t)(p0 + row) * 512;
    const unsigned short* aL = hcL + (size_t)(p0 + row) * 512;
    f32x16 acc[2];
#pragma unroll
    for (int nt = 0; nt < 2; ++nt)
#pragma unroll
        for (int r = 0; r < 16; ++r) acc[nt][r] = 0.f;

#pragma unroll 2
    for (int ks = 0; ks < 32; ++ks) {
        int k0 = ks * 16 + half * 8;
        bf16x8 avh = *(const bf16x8*)(aH + k0);
        bf16x8 avl = *(const bf16x8*)(aL + k0);
#pragma unroll
        for (int nt = 0; nt < 2; ++nt) {
            int j = ob + nt * 32 + row;
            bf16x8 bvh = *(const bf16x8*)(w5H + (size_t)j * 512 + k0);
            bf16x8 bvl = *(const bf16x8*)(w5L + (size_t)j * 512 + k0);
            acc[nt] = __builtin_amdgcn_mfma_f32_32x32x16_bf16(avh, bvh, acc[nt], 0, 0, 0);
            acc[nt] = __builtin_amdgcn_mfma_f32_32x32x16_bf16(avh, bvl, acc[nt], 0, 0, 0);
            acc[nt] = __builtin_amdgcn_mfma_f32_32x32x16_bf16(avl, bvh, acc[nt], 0, 0, 0);
        }
    }
    int slot = blockIdx.x & (SLOTSW - 1);
#pragma unroll
    for (int nt = 0; nt < 2; ++nt) {
        int j = ob + nt * 32 + row;
        float s1 = 0.f, s2 = 0.f;
#pragma unroll
        for (int r = 0; r < 16; ++r) {
            int i = (r & 3) + 8 * (r >> 2) + 4 * half;
            float v = acc[nt][r];
            g5[(size_t)(p0 + i) * 1024 + j] = v;
            s1 += v; s2 += v * v;
        }
        s1 += __shfl_xor(s1, 32);
        s2 += __shfl_xor(s2, 32);
        if (half == 0) {
            atomicAdd(&s1p[slot * 1024 + j], s1);
            atomicAdd(&s2p[slot * 1024 + j], s2);
        }
    }
}

// ---------------- pool: per (b, o-tile, n-chunk) partial max / partial sum
__global__ void k_pool(const float* __restrict__ gbuf, const float* __restrict__ s1g,
                       const float* __restrict__ s2g, const float* __restrict__ gam,
                       const float* __restrict__ bet, float* __restrict__ pmax,
                       float* __restrict__ psum) {
    int t = threadIdx.x;
    int blk = blockIdx.x;
    int nc = blk & 7, ot = (blk >> 3) & 3, b = blk >> 5;
    int o = ot * 256 + t;
    float m = s1g[o] * (1.f / 16384.f);
    float v = s2g[o] * (1.f / 16384.f) - m * m;
    float rs = rsqrtf(v + EPSBN);
    float ga = gam[o], be = bet[o];
    float vmax = NEG, vsum = 0.f;
    for (int j = 0; j < 256; ++j) {
        int n = nc * 256 + j;
        float x = gbuf[((size_t)b * NP + n) * 1024 + o];
        float y = leaky(ga * (x - m) * rs + be);
        vmax = fmaxf(vmax, y);
        vsum += y;
    }
    pmax[(b * 1024 + o) * 8 + nc] = vmax;
    psum[(b * 1024 + o) * 8 + nc] = vsum;
}

__global__ void k_poolfin(const float* __restrict__ pmax, const float* __restrict__ psum,
                          float* __restrict__ pooled) {
    int i = blockIdx.x * 256 + threadIdx.x;
    if (i >= 8192) return;
    float mx = NEG, sm = 0.f;
    for (int j = 0; j < 8; ++j) {
        mx = fmaxf(mx, pmax[i * 8 + j]);
        sm += psum[i * 8 + j];
    }
    int b = i >> 10, o = i & 1023;
    pooled[b * 2048 + o] = mx;
    pooled[b * 2048 + 1024 + o] = sm * (1.f / 2048.f);
}

// ---------------- small FC: z[b][o] = in[b] . W[o] (+bias)
template <int CIN>
__global__ void k_fc(const float* __restrict__ in, const float* __restrict__ W,
                     const float* __restrict__ bias, int O, float* __restrict__ z) {
    int i = blockIdx.x * 256 + threadIdx.x;
    if (i >= NB * O) return;
    int b = i / O, o = i % O;
    const float* wr = W + (size_t)o * CIN;
    const float* ir = in + (size_t)b * CIN;
    float acc = 0.f;
#pragma unroll 4
    for (int cq = 0; cq < CIN / 4; ++cq) {
        float4 wv = *(const float4*)&wr[cq * 4];
        float4 iv = *(const float4*)&ir[cq * 4];
        acc += wv.x * iv.x + wv.y * iv.y + wv.z * iv.z + wv.w * iv.w;
    }
    z[i] = acc + (bias ? bias[o] : 0.f);
}

// ---------------- BN over batch (8 samples) + leaky
__global__ void k_bnb(const float* __restrict__ z, int O, const float* __restrict__ gam,
                      const float* __restrict__ bet, float* __restrict__ out, int ostride,
                      int ooff) {
    int o = blockIdx.x * 256 + threadIdx.x;
    if (o >= O) return;
    float s1 = 0.f, s2 = 0.f;
#pragma unroll
    for (int b = 0; b < NB; ++b) {
        float x = z[b * O + o];
        s1 += x; s2 += x * x;
    }
    float m = s1 * 0.125f, v = s2 * 0.125f - m * m;
    float rs = rsqrtf(v + EPSBN);
    float ga = gam[o], be = bet[o];
    for (int b = 0; b < NB; ++b) {
        float y = ga * (z[b * O + o] - m) * rs + be;
        out[b * ostride + ooff + o] = leaky(y);
    }
}

// ---------------- head
__global__ void k_head(const float* __restrict__ hf, const float* __restrict__ wh,
                       const float* __restrict__ bh, const float* __restrict__ g8,
                       const float* __restrict__ b8, float* __restrict__ out) {
    __shared__ float zh[56];
    int t = threadIdx.x;
    if (t < 56) {
        int b = t / 7, o = t % 7;
        float acc = bh[o];
        for (int c = 0; c < 768; ++c) acc += hf[b * 768 + c] * wh[o * 768 + c];
        zh[t] = acc;
    }
    __syncthreads();
    if (t < 7) {
        float s1 = 0.f, s2 = 0.f;
        for (int b = 0; b < NB; ++b) {
            float x = zh[b * 7 + t];
            s1 += x; s2 += x * x;
        }
        float m = s1 * 0.125f, v = s2 * 0.125f - m * m;
        float rs = rsqrtf(v + EPSBN);
        for (int b = 0; b < NB; ++b) {
            float y = g8[t] * (zh[b * 7 + t] - m) * rs + b8[t];
            out[b * 7 + t] = fmaxf(y, 0.f);
        }
    }
}

extern "C" void kernel_launch(void* const* d_in, const int* in_sizes, int n_in, void* d_out,
                              int out_size, void* d_ws, size_t ws_size, hipStream_t stream) {
    const float* x[3] = {(const float*)d_in[0], (const float*)d_in[1], (const float*)d_in[2]};
    const float* w1 = (const float*)d_in[3];
    const float* w2 = (const float*)d_in[4];
    const float* w3 = (const float*)d_in[5];
    const float* w4 = (const float*)d_in[6];
    const float* w5 = (const float*)d_in[7];
    const float* wl1 = (const float*)d_in[8];
    const float* wl2 = (const float*)d_in[9];
    const float* bl2 = (const float*)d_in[10];
    const float* whead = (const float*)d_in[11];
    const float* bhead = (const float*)d_in[12];
    const float *g1 = (const float*)d_in[13], *b1 = (const float*)d_in[14];
    const float *g2 = (const float*)d_in[15], *b2 = (const float*)d_in[16];
    const float *g3 = (const float*)d_in[17], *b3 = (const float*)d_in[18];
    const float *g4 = (const float*)d_in[19], *b4 = (const float*)d_in[20];
    const float *g5 = (const float*)d_in[21], *b5 = (const float*)d_in[22];
    const float *g6 = (const float*)d_in[23], *b6 = (const float*)d_in[24];
    const float *g7 = (const float*)d_in[25], *b7 = (const float*)d_in[26];
    const float *g8 = (const float*)d_in[27], *b8 = (const float*)d_in[28];

    char* w = (char*)d_ws;
    auto alloc = [&](size_t bytes) {
        char* p = w;
        w += (bytes + 255) & ~(size_t)255;
        return p;
    };
    float* xt   = (float*)alloc((size_t)BN * 4 * 4);
    float* xtT  = (float*)alloc((size_t)4 * BN * 4);
    unsigned short* hcH = (unsigned short*)alloc((size_t)BN * 512 * 2);
    unsigned short* hcL = (unsigned short*)alloc((size_t)BN * 512 * 2);
    float* hcT  = (float*)alloc((size_t)128 * BN * 4);
    float* gbig = (float*)alloc((size_t)BN * 1024 * 4);  // Gz[0,BN*512) | hmax@BN*512 | g5 full
    int*   idx  = (int*)alloc((size_t)BN * KK * 4);
    float* sqv  = (float*)alloc((size_t)BN * 4);
    float* s1g  = (float*)alloc(1024 * 4);
    float* s2g  = (float*)alloc(1024 * 4);
    float* spart  = (float*)alloc(2 * SLOTS * 256 * 4);     // conv1 fp32 stats
    float* spartC = (float*)alloc(2 * SLOTSM * 256 * 4);    // gmax stats
    float* spartW = (float*)alloc(2 * SLOTSW * 1024 * 4);   // w5 stats
    float* pmax = (float*)alloc(8 * 1024 * 8 * 4);
    float* psum = (float*)alloc(8 * 1024 * 8 * 4);
    float* pooled = (float*)alloc(8 * 2048 * 4);
    float* z1 = (float*)alloc(8 * 512 * 4);
    float* a1 = (float*)alloc(8 * 512 * 4);
    float* z2 = (float*)alloc(8 * 256 * 4);
    float* hfeat = (float*)alloc(8 * 768 * 4);
    float* Wa1 = (float*)alloc(4 * 64 * 4);
    float* Wd1 = (float*)alloc(4 * 64 * 4);
    unsigned short* WcH2 = (unsigned short*)alloc(128 * 64 * 2);
    unsigned short* WcL2 = (unsigned short*)alloc(128 * 64 * 2);
    unsigned short* WcH3 = (unsigned short*)alloc(256 * 64 * 2);
    unsigned short* WcL3 = (unsigned short*)alloc(256 * 64 * 2);
    unsigned short* WcH4 = (unsigned short*)alloc(512 * 128 * 2);
    unsigned short* WcL4 = (unsigned short*)alloc(512 * 128 * 2);
    unsigned short* w5H  = (unsigned short*)alloc(1024 * 512 * 2);
    unsigned short* w5L  = (unsigned short*)alloc(1024 * 512 * 2);
    float* s1p = spart;
    float* s2p = spart + SLOTS * 256;
    float* s1pc = spartC;
    float* s2pc = spartC + SLOTSM * 256;
    float* s1pw = spartW;
    float* s2pw = spartW + SLOTSW * 1024;
    float* hmaxP = gbig + (size_t)BN * 512;   // disjoint from Gz region [0, BN*512)

    // weight prep (plane-independent)
    k_prepw<<<(4 * 64 + 255) / 256, 256, 0, stream>>>(w1, 64, 3, 4, Wa1, Wd1);
    k_prepws2<<<(128 * 64 + 255) / 256, 256, 0, stream>>>(w2, 64, 64, WcH2, WcL2);
    k_prepws2<<<(256 * 64 + 255) / 256, 256, 0, stream>>>(w3, 128, 64, WcH3, WcL3);
    k_prepws2<<<(512 * 128 + 255) / 256, 256, 0, stream>>>(w4, 256, 128, WcH4, WcL4);
    k_splitw5<<<(1024 * 512) / 256, 256, 0, stream>>>(w5, w5H, w5L);

    const float inv_e = 1.f / (float)(BN * KK);
    for (int p = 0; p < 3; ++p) {
        k_transpose<<<BN / 256, 256, 0, stream>>>(x[p], xt, xtT);

        // ---- layer 1 (fp32): C=3 pad 4, O=64 -> cols 0:64
        k_sq<4><<<BN / 256, 256, 0, stream>>>(xtT, sqv);
        k_knn<4><<<NB * (NP / 8), 256, 0, stream>>>(xtT, sqv, idx);
        hipMemsetAsync(spart, 0, 2 * SLOTS * 256 * 4, stream);
        k_conv<64, 4><<<BN / 2, 64, 0, stream>>>(xt, 4, idx, Wa1, Wd1, hmaxP, s1p, s2p);
        k_redslots<<<1, 256, 0, stream>>>(s1p, s2p, 64, SLOTS, s1g, s2g);
        k_bnmax<<<(BN * 64) / 256, 256, 0, stream>>>(hmaxP, 64, s1g, s2g, g1, b1, hcH, hcL, 512, 0, inv_e);
        k_xposeB<<<dim3(BN / 64, 1), 256, 0, stream>>>(hcH, hcL, 0, hcT);

        // ---- layer 2: dense Gz=[G|bacc] (O2=128) + gather-max
        k_sq<64><<<BN / 256, 256, 0, stream>>>(hcT, sqv);
        k_knn<64><<<NB * (NP / 8), 256, 0, stream>>>(hcT, sqv, idx);
        k_gemms<128, 64, 0><<<dim3(BN / 128, 2), 256, 0, stream>>>(hcH, hcL, WcH2, WcL2, gbig);
        hipMemsetAsync(spartC, 0, 2 * SLOTSM * 256 * 4, stream);
        k_gmax<64><<<BN / 4, 256, 0, stream>>>(gbig, idx, hmaxP, s1pc, s2pc);
        k_redslots<<<1, 256, 0, stream>>>(s1pc, s2pc, 64, SLOTSM, s1g, s2g);
        k_bnmax<<<(BN * 64) / 256, 256, 0, stream>>>(hmaxP, 64, s1g, s2g, g2, b2, hcH, hcL, 512, 64, inv_e);
        k_xposeB<<<dim3(BN / 64, 1), 256, 0, stream>>>(hcH, hcL, 64, hcT);

        // ---- layer 3: O2=256
        k_sq<64><<<BN / 256, 256, 0, stream>>>(hcT, sqv);
        k_knn<64><<<NB * (NP / 8), 256, 0, stream>>>(hcT, sqv, idx);
        k_gemms<256, 64, 64><<<dim3(BN / 128, 4), 256, 0, stream>>>(hcH, hcL, WcH3, WcL3, gbig);
        hipMemsetAsync(spartC, 0, 2 * SLOTSM * 256 * 4, stream);
        k_gmax<128><<<BN / 2, 256, 0, stream>>>(gbig, idx, hmaxP, s1pc, s2pc);
        k_redslots<<<1, 256, 0, stream>>>(s1pc, s2pc, 128, SLOTSM, s1g, s2g);
        k_bnmax<<<(BN * 128) / 256, 256, 0, stream>>>(hmaxP, 128, s1g, s2g, g3, b3, hcH, hcL, 512, 128, inv_e);
        k_xposeB<<<dim3(BN / 64, 2), 256, 0, stream>>>(hcH, hcL, 128, hcT);

        // ---- layer 4: O2=512
        k_sq<128><<<BN / 256, 256, 0, stream>>>(hcT, sqv);
        k_knn<128><<<NB * (NP / 8), 256, 0, stream>>>(hcT, sqv, idx);
        k_gemms<512, 128, 128><<<dim3(BN / 128, 8), 256, 0, stream>>>(hcH, hcL, WcH4, WcL4, gbig);
        hipMemsetAsync(spartC, 0, 2 * SLOTSM * 256 * 4, stream);
        k_gmax<256><<<BN, 256, 0, stream>>>(gbig, idx, hmaxP, s1pc, s2pc);
        k_redslots<<<1, 256, 0, stream>>>(s1pc, s2pc, 256, SLOTSM, s1g, s2g);
        k_bnmax<<<(BN * 256) / 256, 256, 0, stream>>>(hmaxP, 256, s1g, s2g, g4, b4, hcH, hcL, 512, 256, inv_e);

        // ---- w5 (mfma split) + BN + pool
        hipMemsetAsync(spartW, 0, 2 * SLOTSW * 1024 * 4, stream);
        k_w5ms<<<dim3(BN / 32, 4), 256, 0, stream>>>(hcH, hcL, w5H, w5L, gbig, s1pw, s2pw);
        k_redslots<<<4, 256, 0, stream>>>(s1pw, s2pw, 1024, SLOTSW, s1g, s2g);
        k_pool<<<256, 256, 0, stream>>>(gbig, s1g, s2g, g5, b5, pmax, psum);
        k_poolfin<<<32, 256, 0, stream>>>(pmax, psum, pooled);

        // ---- FC head of the plane
        k_fc<2048><<<(8 * 512 + 255) / 256, 256, 0, stream>>>(pooled, wl1, nullptr, 512, z1);
        k_bnb<<<2, 256, 0, stream>>>(z1, 512, g6, b6, a1, 512, 0);
        k_fc<512><<<(8 * 256 + 255) / 256, 256, 0, stream>>>(a1, wl2, bl2, 256, z2);
        k_bnb<<<1, 256, 0, stream>>>(z2, 256, g7, b7, hfeat, 768, p * 256);
    }
    k_head<<<1, 64, 0, stream>>>(hfeat, whead, bhead, g8, b8, (float*)d_out);
}